// Round 3
// baseline (4452.695 us; speedup 1.0000x reference)
//
#include <hip/hip_runtime.h>

#define HDIM 128
#define NT 32
#define LST 34   // NT + 2: keeps (k*LST + even)*4 8-byte aligned for float2 LDS reads

// ---------------- CSR build kernels ----------------

__global__ void hist_kernel(const int* __restrict__ dst, int* __restrict__ deg, int E) {
  int e = blockIdx.x * 256 + threadIdx.x;
  if (e < E) atomicAdd(&deg[dst[e]], 1);
}

__global__ void scan_block_sum(const int* __restrict__ deg, int* __restrict__ partials, int n) {
  __shared__ int red[256];
  int t = threadIdx.x;
  int base = blockIdx.x * 4096;
  int s = 0;
  #pragma unroll
  for (int i = 0; i < 16; ++i) {
    int idx = base + t + i * 256;
    if (idx < n) s += deg[idx];
  }
  red[t] = s;
  __syncthreads();
  for (int o = 128; o > 0; o >>= 1) {
    if (t < o) red[t] += red[t + o];
    __syncthreads();
  }
  if (t == 0) partials[blockIdx.x] = red[0];
}

__global__ void scan_partials_kernel(int* __restrict__ partials, int* __restrict__ rowptr,
                                     int nb, int n) {
  // single thread: nb <= 49
  int run = 0;
  for (int i = 0; i < nb; ++i) { int v = partials[i]; partials[i] = run; run += v; }
  rowptr[n] = run;
}

__global__ void scan_within(int* __restrict__ deg_cursor, const int* __restrict__ partials,
                            int* __restrict__ rowptr, int n) {
  __shared__ int buf[4096];
  __shared__ int wsum[4];
  int t = threadIdx.x;
  int base = blockIdx.x * 4096;
  #pragma unroll
  for (int i = 0; i < 16; ++i) {
    int idx = base + t + i * 256;
    buf[t + i * 256] = (idx < n) ? deg_cursor[idx] : 0;
  }
  __syncthreads();
  int ex[16];
  int s = 0;
  #pragma unroll
  for (int i = 0; i < 16; ++i) { ex[i] = s; s += buf[t * 16 + i]; }
  int lane = t & 63, w = t >> 6;
  int v = s;
  #pragma unroll
  for (int o = 1; o < 64; o <<= 1) {
    int u = __shfl_up(v, o);
    if (lane >= o) v += u;
  }
  if (lane == 63) wsum[w] = v;
  __syncthreads();
  int off = partials[blockIdx.x] + (v - s);
  for (int i = 0; i < w; ++i) off += wsum[i];
  #pragma unroll
  for (int i = 0; i < 16; ++i) {
    int idx = base + t * 16 + i;
    if (idx < n) { int val = off + ex[i]; rowptr[idx] = val; deg_cursor[idx] = val; }
  }
}

__global__ void scatter_kernel(const int* __restrict__ src, const int* __restrict__ dst,
                               int* __restrict__ cursor, int* __restrict__ col, int E) {
  int e = blockIdx.x * 256 + threadIdx.x;
  if (e < E) {
    int p = atomicAdd(&cursor[dst[e]], 1);
    col[p] = src[e];
  }
}

// ---------------- fused SAGE kernel ----------------
// mode: 0 = write norm (no lrelu), 1 = write lrelu(norm), 2 = out = lrelu(out + norm)

__device__ __forceinline__ void write_row(float* __restrict__ out, int node, int j0,
                                          const float (&acc)[8], float inv, int mode) {
  float o[8];
  #pragma unroll
  for (int b = 0; b < 8; ++b) o[b] = acc[b] * inv;
  float* p = out + node * HDIM + j0;
  if (mode == 2) {
    float4 p0 = *(const float4*)&p[0];
    float4 p1 = *(const float4*)&p[4];
    float prev[8] = {p0.x, p0.y, p0.z, p0.w, p1.x, p1.y, p1.z, p1.w};
    #pragma unroll
    for (int b = 0; b < 8; ++b) {
      float v = o[b] + prev[b];
      o[b] = (v >= 0.f) ? v : 0.01f * v;
    }
  } else if (mode == 1) {
    #pragma unroll
    for (int b = 0; b < 8; ++b) o[b] = (o[b] >= 0.f) ? o[b] : 0.01f * o[b];
  }
  float4 q0 = {o[0], o[1], o[2], o[3]};
  float4 q1 = {o[4], o[5], o[6], o[7]};
  *(float4*)&p[0] = q0;
  *(float4*)&p[4] = q1;
}

__global__ __launch_bounds__(256) void sage_kernel(
    const float* __restrict__ xsrc, const float* __restrict__ xdst,
    const int* __restrict__ rowptr, const int* __restrict__ colidx,
    const float* __restrict__ Wl, const float* __restrict__ bl, const float* __restrict__ Wr,
    float* __restrict__ out, int n_dst, int mode)
{
  __shared__ float lds_a[HDIM * LST];   // agg, [feature][node]
  __shared__ float lds_x[HDIM * LST];   // xdst, [feature][node]
  __shared__ float lds_red[NT * 16];

  int tid = threadIdx.x;
  int n0 = blockIdx.x * NT;

  // ---- phase 1: mean-aggregate + root-feature load into LDS ----
  {
    int f = tid & (HDIM - 1);
    int sub = tid >> 7;   // 0 or 1 -> two nodes processed in parallel
    for (int ni = sub; ni < NT; ni += 2) {
      int node = n0 + ni;
      float acc = 0.f, xd = 0.f;
      if (node < n_dst) {
        int beg = rowptr[node];
        int end = rowptr[node + 1];
        xd = xdst[node * HDIM + f];
        for (int e = beg; e < end; ++e) {
          acc += xsrc[colidx[e] * HDIM + f];
        }
        int dg = end - beg;
        if (dg > 0) acc = acc / (float)dg;
      }
      lds_a[f * LST + ni] = acc;
      lds_x[f * LST + ni] = xd;
    }
  }
  __syncthreads();

  // ---- phase 2: register-tiled GEMM: out = agg@Wl + bl + xd@Wr ----
  int jg = tid & 15;   // feature group: j0..j0+7, adjacent lanes -> adjacent feats (coalesced)
  int ng = tid >> 4;   // node group: nodes na, na+1
  int j0 = jg * 8, na = ng * 2;

  float acc0[8], acc1[8];
  {
    float4 b0 = *(const float4*)&bl[j0];
    float4 b1 = *(const float4*)&bl[j0 + 4];
    float bb[8] = {b0.x, b0.y, b0.z, b0.w, b1.x, b1.y, b1.z, b1.w};
    #pragma unroll
    for (int b = 0; b < 8; ++b) { acc0[b] = bb[b]; acc1[b] = bb[b]; }
  }

  #pragma unroll 4
  for (int k = 0; k < HDIM; ++k) {
    float2 av = *(const float2*)&lds_a[k * LST + na];
    float2 xv = *(const float2*)&lds_x[k * LST + na];
    float4 wl0 = *(const float4*)&Wl[k * HDIM + j0];
    float4 wl1 = *(const float4*)&Wl[k * HDIM + j0 + 4];
    float4 wr0 = *(const float4*)&Wr[k * HDIM + j0];
    float4 wr1 = *(const float4*)&Wr[k * HDIM + j0 + 4];
    float wl[8] = {wl0.x, wl0.y, wl0.z, wl0.w, wl1.x, wl1.y, wl1.z, wl1.w};
    float wr[8] = {wr0.x, wr0.y, wr0.z, wr0.w, wr1.x, wr1.y, wr1.z, wr1.w};
    #pragma unroll
    for (int b = 0; b < 8; ++b) {
      acc0[b] += av.x * wl[b] + xv.x * wr[b];
      acc1[b] += av.y * wl[b] + xv.y * wr[b];
    }
  }

  // ---- phase 3: row norms via LDS reduction, normalize, write ----
  float ss0 = 0.f, ss1 = 0.f;
  #pragma unroll
  for (int b = 0; b < 8; ++b) { ss0 += acc0[b] * acc0[b]; ss1 += acc1[b] * acc1[b]; }
  lds_red[na * 16 + jg] = ss0;
  lds_red[(na + 1) * 16 + jg] = ss1;
  __syncthreads();
  float nrm0 = 0.f, nrm1 = 0.f;
  #pragma unroll
  for (int i = 0; i < 16; ++i) {
    nrm0 += lds_red[na * 16 + i];
    nrm1 += lds_red[(na + 1) * 16 + i];
  }
  float inv0 = 1.0f / fmaxf(sqrtf(nrm0), 1e-12f);
  float inv1 = 1.0f / fmaxf(sqrtf(nrm1), 1e-12f);

  int node0 = n0 + na;
  int node1 = node0 + 1;
  if (node0 < n_dst) write_row(out, node0, j0, acc0, inv0, mode);
  if (node1 < n_dst) write_row(out, node1, j0, acc1, inv1, mode);
}

// ---------------- host launch ----------------

extern "C" void kernel_launch(void* const* d_in, const int* in_sizes, int n_in,
                              void* d_out, int out_size, void* d_ws, size_t ws_size,
                              hipStream_t stream) {
  (void)n_in; (void)out_size; (void)ws_size;
  const float* x_ip  = (const float*)d_in[0];
  const float* x_con = (const float*)d_in[1];
  const int* src_ipcon = (const int*)d_in[2];
  const int* dst_ipcon = (const int*)d_in[3];
  const int* src_conip = (const int*)d_in[4];
  const int* dst_conip = (const int*)d_in[5];
  const int* src_ipip  = (const int*)d_in[6];
  const int* dst_ipip  = (const int*)d_in[7];
  const int* src_csrc  = (const int*)d_in[8];
  const int* dst_csrc  = (const int*)d_in[9];
  const int* src_cdst  = (const int*)d_in[10];
  const int* dst_cdst  = (const int*)d_in[11];
  const float* Wl_t = (const float*)d_in[12];
  const float* bl_t = (const float*)d_in[13];
  const float* Wr_t = (const float*)d_in[14];
  const float* Wl_s = (const float*)d_in[15];
  const float* bl_s = (const float*)d_in[16];
  const float* Wr_s = (const float*)d_in[17];

  const int n_ip  = in_sizes[0] / HDIM;
  const int n_con = in_sizes[1] / HDIM;
  const int E_ipcon = in_sizes[2];
  const int E_conip = in_sizes[4];
  const int E_ipip  = in_sizes[6];
  const int E_csrc  = in_sizes[8];
  const int E_cdst  = in_sizes[10];

  char* ws = (char*)d_ws;
  size_t off = 0;
  auto alloc = [&](size_t bytes) -> void* {
    off = (off + 255) & ~(size_t)255;
    void* p = ws + off;
    off += bytes;
    return p;
  };
  float* Y_ip  = (float*)alloc((size_t)n_ip * HDIM * 4);
  float* Y_con = (float*)alloc((size_t)n_con * HDIM * 4);
  int* cur_all = (int*)alloc((size_t)(2 * n_ip + 3 * n_con) * 4);
  int* cur_ipip  = cur_all;
  int* cur_csrc  = cur_ipip + n_ip;
  int* cur_cdst  = cur_csrc + n_con;
  int* cur_ipcon = cur_cdst + n_con;
  int* cur_conip = cur_ipcon + n_con;
  int* rp_ipip  = (int*)alloc((size_t)(n_ip + 1) * 4);
  int* rp_csrc  = (int*)alloc((size_t)(n_con + 1) * 4);
  int* rp_cdst  = (int*)alloc((size_t)(n_con + 1) * 4);
  int* rp_ipcon = (int*)alloc((size_t)(n_con + 1) * 4);
  int* rp_conip = (int*)alloc((size_t)(n_ip + 1) * 4);
  int* col_ipip  = (int*)alloc((size_t)E_ipip * 4);
  int* col_csrc  = (int*)alloc((size_t)E_csrc * 4);
  int* col_cdst  = (int*)alloc((size_t)E_cdst * 4);
  int* col_ipcon = (int*)alloc((size_t)E_ipcon * 4);
  int* col_conip = (int*)alloc((size_t)E_conip * 4);
  int* partials  = (int*)alloc(256 * 4);

  hipMemsetAsync(cur_all, 0, (size_t)(2 * n_ip + 3 * n_con) * 4, stream);

  auto build = [&](const int* src, const int* dst, int E, int n, int* cur, int* rp, int* col) {
    hist_kernel<<<(E + 255) / 256, 256, 0, stream>>>(dst, cur, E);
    int nb = (n + 4095) / 4096;
    scan_block_sum<<<nb, 256, 0, stream>>>(cur, partials, n);
    scan_partials_kernel<<<1, 1, 0, stream>>>(partials, rp, nb, n);
    scan_within<<<nb, 256, 0, stream>>>(cur, partials, rp, n);
    scatter_kernel<<<(E + 255) / 256, 256, 0, stream>>>(src, dst, cur, col, E);
  };
  build(src_ipip,  dst_ipip,  E_ipip,  n_ip,  cur_ipip,  rp_ipip,  col_ipip);
  build(src_csrc,  dst_csrc,  E_csrc,  n_con, cur_csrc,  rp_csrc,  col_csrc);
  build(src_cdst,  dst_cdst,  E_cdst,  n_con, cur_cdst,  rp_cdst,  col_cdst);
  build(src_ipcon, dst_ipcon, E_ipcon, n_con, cur_ipcon, rp_ipcon, col_ipcon);
  build(src_conip, dst_conip, E_conip, n_ip,  cur_conip, rp_conip, col_conip);

  float* out_ip  = (float*)d_out;
  float* out_con = (float*)d_out + (size_t)n_ip * HDIM;

  auto sage = [&](const float* xs, const float* xd, const int* rp, const int* col,
                  const float* Wl, const float* bl, const float* Wr,
                  float* o, int n, int mode) {
    sage_kernel<<<(n + NT - 1) / NT, 256, 0, stream>>>(xs, xd, rp, col, Wl, bl, Wr, o, n, mode);
  };

  const float* cip  = x_ip;
  const float* ccon = x_con;
  for (int l = 0; l < 2; ++l) {
    // temporal heteroconv
    sage(cip,  cip,  rp_ipip, col_ipip,
         Wl_t + (l * 3 + 0) * HDIM * HDIM, bl_t + (l * 3 + 0) * HDIM, Wr_t + (l * 3 + 0) * HDIM * HDIM,
         Y_ip, n_ip, 1);
    sage(ccon, ccon, rp_csrc, col_csrc,
         Wl_t + (l * 3 + 1) * HDIM * HDIM, bl_t + (l * 3 + 1) * HDIM, Wr_t + (l * 3 + 1) * HDIM * HDIM,
         Y_con, n_con, 0);
    sage(ccon, ccon, rp_cdst, col_cdst,
         Wl_t + (l * 3 + 2) * HDIM * HDIM, bl_t + (l * 3 + 2) * HDIM, Wr_t + (l * 3 + 2) * HDIM * HDIM,
         Y_con, n_con, 2);
    // spatial heteroconv (reads temporal outputs Y_*)
    sage(Y_ip,  Y_con, rp_ipcon, col_ipcon,
         Wl_s + (l * 2 + 0) * HDIM * HDIM, bl_s + (l * 2 + 0) * HDIM, Wr_s + (l * 2 + 0) * HDIM * HDIM,
         out_con, n_con, 1);
    sage(Y_con, Y_ip,  rp_conip, col_conip,
         Wl_s + (l * 2 + 1) * HDIM * HDIM, bl_s + (l * 2 + 1) * HDIM, Wr_s + (l * 2 + 1) * HDIM * HDIM,
         out_ip, n_ip, 1);
    cip = out_ip;
    ccon = out_con;
  }
}

// Round 4
// 4439.734 us; speedup vs baseline: 1.0029x; 1.0029x over previous
//
#include <hip/hip_runtime.h>

#define HDIM 128
#define NT 32
#define LST 34   // NT + 2: keeps (k*LST + even)*4 8-byte aligned for float2 LDS reads

// ---------------- CSR build kernels ----------------

__global__ void hist_kernel(const int* __restrict__ dst, int* __restrict__ deg, int E) {
  int e = blockIdx.x * 256 + threadIdx.x;
  if (e < E) atomicAdd(&deg[dst[e]], 1);
}

__global__ void scan_block_sum(const int* __restrict__ deg, int* __restrict__ partials, int n) {
  __shared__ int red[256];
  int t = threadIdx.x;
  int base = blockIdx.x * 4096;
  int s = 0;
  #pragma unroll
  for (int i = 0; i < 16; ++i) {
    int idx = base + t + i * 256;
    if (idx < n) s += deg[idx];
  }
  red[t] = s;
  __syncthreads();
  for (int o = 128; o > 0; o >>= 1) {
    if (t < o) red[t] += red[t + o];
    __syncthreads();
  }
  if (t == 0) partials[blockIdx.x] = red[0];
}

__global__ void scan_partials_kernel(int* __restrict__ partials, int* __restrict__ rowptr,
                                     int nb, int n) {
  // single thread: nb <= 49
  int run = 0;
  for (int i = 0; i < nb; ++i) { int v = partials[i]; partials[i] = run; run += v; }
  rowptr[n] = run;
}

__global__ void scan_within(int* __restrict__ deg_cursor, const int* __restrict__ partials,
                            int* __restrict__ rowptr, int n) {
  __shared__ int buf[4096];
  __shared__ int wsum[4];
  int t = threadIdx.x;
  int base = blockIdx.x * 4096;
  #pragma unroll
  for (int i = 0; i < 16; ++i) {
    int idx = base + t + i * 256;
    buf[t + i * 256] = (idx < n) ? deg_cursor[idx] : 0;
  }
  __syncthreads();
  int ex[16];
  int s = 0;
  #pragma unroll
  for (int i = 0; i < 16; ++i) { ex[i] = s; s += buf[t * 16 + i]; }
  int lane = t & 63, w = t >> 6;
  int v = s;
  #pragma unroll
  for (int o = 1; o < 64; o <<= 1) {
    int u = __shfl_up(v, o);
    if (lane >= o) v += u;
  }
  if (lane == 63) wsum[w] = v;
  __syncthreads();
  int off = partials[blockIdx.x] + (v - s);
  for (int i = 0; i < w; ++i) off += wsum[i];
  #pragma unroll
  for (int i = 0; i < 16; ++i) {
    int idx = base + t * 16 + i;
    if (idx < n) { int val = off + ex[i]; rowptr[idx] = val; deg_cursor[idx] = val; }
  }
}

__global__ void scatter_kernel(const int* __restrict__ src, const int* __restrict__ dst,
                               int* __restrict__ cursor, int* __restrict__ col, int E) {
  int e = blockIdx.x * 256 + threadIdx.x;
  if (e < E) {
    int p = atomicAdd(&cursor[dst[e]], 1);
    col[p] = src[e];
  }
}

// ---------------- fused SAGE kernel ----------------
// mode: 0 = write norm (no lrelu), 1 = write lrelu(norm), 2 = out = lrelu(out + norm)

__device__ __forceinline__ void write_row(float* __restrict__ out, int node, int j0,
                                          const float (&acc)[8], float inv, int mode) {
  float o[8];
  #pragma unroll
  for (int b = 0; b < 8; ++b) o[b] = acc[b] * inv;
  float* p = out + node * HDIM + j0;
  if (mode == 2) {
    float4 p0 = *(const float4*)&p[0];
    float4 p1 = *(const float4*)&p[4];
    float prev[8] = {p0.x, p0.y, p0.z, p0.w, p1.x, p1.y, p1.z, p1.w};
    #pragma unroll
    for (int b = 0; b < 8; ++b) {
      float v = o[b] + prev[b];
      o[b] = (v >= 0.f) ? v : 0.01f * v;
    }
  } else if (mode == 1) {
    #pragma unroll
    for (int b = 0; b < 8; ++b) o[b] = (o[b] >= 0.f) ? o[b] : 0.01f * o[b];
  }
  float4 q0 = {o[0], o[1], o[2], o[3]};
  float4 q1 = {o[4], o[5], o[6], o[7]};
  *(float4*)&p[0] = q0;
  *(float4*)&p[4] = q1;
}

__global__ __launch_bounds__(256) void sage_kernel(
    const float* __restrict__ xsrc, const float* __restrict__ xdst,
    const int* __restrict__ rowptr, const int* __restrict__ colidx,
    const float* __restrict__ Wl, const float* __restrict__ bl, const float* __restrict__ Wr,
    float* __restrict__ out, int n_dst, int mode)
{
  __shared__ float lds_a[HDIM * LST];   // agg, [feature][node]
  __shared__ float lds_x[HDIM * LST];   // xdst, [feature][node]
  __shared__ float lds_red[NT * 16];

  int tid = threadIdx.x;
  int n0 = blockIdx.x * NT;

  // ---- phase 1: mean-aggregate + root-feature load into LDS ----
  {
    int f = tid & (HDIM - 1);
    int sub = tid >> 7;   // 0 or 1 -> two nodes processed in parallel
    for (int ni = sub; ni < NT; ni += 2) {
      int node = n0 + ni;
      float acc = 0.f, xd = 0.f;
      if (node < n_dst) {
        int beg = rowptr[node];
        int end = rowptr[node + 1];
        xd = xdst[node * HDIM + f];
        for (int e = beg; e < end; ++e) {
          acc += xsrc[colidx[e] * HDIM + f];
        }
        int dg = end - beg;
        if (dg > 0) acc = acc / (float)dg;
      }
      lds_a[f * LST + ni] = acc;
      lds_x[f * LST + ni] = xd;
    }
  }
  __syncthreads();

  // ---- phase 2: register-tiled GEMM: out = agg@Wl + bl + xd@Wr ----
  int jg = tid & 15;   // feature group: j0..j0+7, adjacent lanes -> adjacent feats (coalesced)
  int ng = tid >> 4;   // node group: nodes na, na+1
  int j0 = jg * 8, na = ng * 2;

  float acc0[8], acc1[8];
  {
    float4 b0 = *(const float4*)&bl[j0];
    float4 b1 = *(const float4*)&bl[j0 + 4];
    float bb[8] = {b0.x, b0.y, b0.z, b0.w, b1.x, b1.y, b1.z, b1.w};
    #pragma unroll
    for (int b = 0; b < 8; ++b) { acc0[b] = bb[b]; acc1[b] = bb[b]; }
  }

  #pragma unroll 4
  for (int k = 0; k < HDIM; ++k) {
    float2 av = *(const float2*)&lds_a[k * LST + na];
    float2 xv = *(const float2*)&lds_x[k * LST + na];
    float4 wl0 = *(const float4*)&Wl[k * HDIM + j0];
    float4 wl1 = *(const float4*)&Wl[k * HDIM + j0 + 4];
    float4 wr0 = *(const float4*)&Wr[k * HDIM + j0];
    float4 wr1 = *(const float4*)&Wr[k * HDIM + j0 + 4];
    float wl[8] = {wl0.x, wl0.y, wl0.z, wl0.w, wl1.x, wl1.y, wl1.z, wl1.w};
    float wr[8] = {wr0.x, wr0.y, wr0.z, wr0.w, wr1.x, wr1.y, wr1.z, wr1.w};
    #pragma unroll
    for (int b = 0; b < 8; ++b) {
      acc0[b] += av.x * wl[b] + xv.x * wr[b];
      acc1[b] += av.y * wl[b] + xv.y * wr[b];
    }
  }

  // ---- phase 3: row norms via LDS reduction, normalize, write ----
  float ss0 = 0.f, ss1 = 0.f;
  #pragma unroll
  for (int b = 0; b < 8; ++b) { ss0 += acc0[b] * acc0[b]; ss1 += acc1[b] * acc1[b]; }
  lds_red[na * 16 + jg] = ss0;
  lds_red[(na + 1) * 16 + jg] = ss1;
  __syncthreads();
  float nrm0 = 0.f, nrm1 = 0.f;
  #pragma unroll
  for (int i = 0; i < 16; ++i) {
    nrm0 += lds_red[na * 16 + i];
    nrm1 += lds_red[(na + 1) * 16 + i];
  }
  float inv0 = 1.0f / fmaxf(sqrtf(nrm0), 1e-12f);
  float inv1 = 1.0f / fmaxf(sqrtf(nrm1), 1e-12f);

  int node0 = n0 + na;
  int node1 = node0 + 1;
  if (node0 < n_dst) write_row(out, node0, j0, acc0, inv0, mode);
  if (node1 < n_dst) write_row(out, node1, j0, acc1, inv1, mode);
}

// ---------------- host launch ----------------

extern "C" void kernel_launch(void* const* d_in, const int* in_sizes, int n_in,
                              void* d_out, int out_size, void* d_ws, size_t ws_size,
                              hipStream_t stream) {
  (void)n_in; (void)out_size; (void)ws_size;
  const float* x_ip  = (const float*)d_in[0];
  const float* x_con = (const float*)d_in[1];
  const int* src_ipcon = (const int*)d_in[2];
  const int* dst_ipcon = (const int*)d_in[3];
  const int* src_conip = (const int*)d_in[4];
  const int* dst_conip = (const int*)d_in[5];
  const int* src_ipip  = (const int*)d_in[6];
  const int* dst_ipip  = (const int*)d_in[7];
  const int* src_csrc  = (const int*)d_in[8];
  const int* dst_csrc  = (const int*)d_in[9];
  const int* src_cdst  = (const int*)d_in[10];
  const int* dst_cdst  = (const int*)d_in[11];
  const float* Wl_t = (const float*)d_in[12];
  const float* bl_t = (const float*)d_in[13];
  const float* Wr_t = (const float*)d_in[14];
  const float* Wl_s = (const float*)d_in[15];
  const float* bl_s = (const float*)d_in[16];
  const float* Wr_s = (const float*)d_in[17];

  const int n_ip  = in_sizes[0] / HDIM;
  const int n_con = in_sizes[1] / HDIM;
  const int E_ipcon = in_sizes[2];
  const int E_conip = in_sizes[4];
  const int E_ipip  = in_sizes[6];
  const int E_csrc  = in_sizes[8];
  const int E_cdst  = in_sizes[10];

  char* ws = (char*)d_ws;
  size_t off = 0;
  auto alloc = [&](size_t bytes) -> void* {
    off = (off + 255) & ~(size_t)255;
    void* p = ws + off;
    off += bytes;
    return p;
  };
  float* Y_ip  = (float*)alloc((size_t)n_ip * HDIM * 4);
  float* Y_con = (float*)alloc((size_t)n_con * HDIM * 4);
  int* cur_all = (int*)alloc((size_t)(2 * n_ip + 3 * n_con) * 4);
  int* cur_ipip  = cur_all;
  int* cur_csrc  = cur_ipip + n_ip;
  int* cur_cdst  = cur_csrc + n_con;
  int* cur_ipcon = cur_cdst + n_con;
  int* cur_conip = cur_ipcon + n_con;
  int* rp_ipip  = (int*)alloc((size_t)(n_ip + 1) * 4);
  int* rp_csrc  = (int*)alloc((size_t)(n_con + 1) * 4);
  int* rp_cdst  = (int*)alloc((size_t)(n_con + 1) * 4);
  int* rp_ipcon = (int*)alloc((size_t)(n_con + 1) * 4);
  int* rp_conip = (int*)alloc((size_t)(n_ip + 1) * 4);
  int* col_ipip  = (int*)alloc((size_t)E_ipip * 4);
  int* col_csrc  = (int*)alloc((size_t)E_csrc * 4);
  int* col_cdst  = (int*)alloc((size_t)E_cdst * 4);
  int* col_ipcon = (int*)alloc((size_t)E_ipcon * 4);
  int* col_conip = (int*)alloc((size_t)E_conip * 4);
  int* partials  = (int*)alloc(256 * 4);

  hipMemsetAsync(cur_all, 0, (size_t)(2 * n_ip + 3 * n_con) * 4, stream);

  auto build = [&](const int* src, const int* dst, int E, int n, int* cur, int* rp, int* col) {
    hist_kernel<<<(E + 255) / 256, 256, 0, stream>>>(dst, cur, E);
    int nb = (n + 4095) / 4096;
    scan_block_sum<<<nb, 256, 0, stream>>>(cur, partials, n);
    scan_partials_kernel<<<1, 1, 0, stream>>>(partials, rp, nb, n);
    scan_within<<<nb, 256, 0, stream>>>(cur, partials, rp, n);
    scatter_kernel<<<(E + 255) / 256, 256, 0, stream>>>(src, dst, cur, col, E);
  };
  build(src_ipip,  dst_ipip,  E_ipip,  n_ip,  cur_ipip,  rp_ipip,  col_ipip);
  build(src_csrc,  dst_csrc,  E_csrc,  n_con, cur_csrc,  rp_csrc,  col_csrc);
  build(src_cdst,  dst_cdst,  E_cdst,  n_con, cur_cdst,  rp_cdst,  col_cdst);
  build(src_ipcon, dst_ipcon, E_ipcon, n_con, cur_ipcon, rp_ipcon, col_ipcon);
  build(src_conip, dst_conip, E_conip, n_ip,  cur_conip, rp_conip, col_conip);

  float* out_ip  = (float*)d_out;
  float* out_con = (float*)d_out + (size_t)n_ip * HDIM;

  auto sage = [&](const float* xs, const float* xd, const int* rp, const int* col,
                  const float* Wl, const float* bl, const float* Wr,
                  float* o, int n, int mode) {
    sage_kernel<<<(n + NT - 1) / NT, 256, 0, stream>>>(xs, xd, rp, col, Wl, bl, Wr, o, n, mode);
  };

  const float* cip  = x_ip;
  const float* ccon = x_con;
  for (int l = 0; l < 2; ++l) {
    // temporal heteroconv
    sage(cip,  cip,  rp_ipip, col_ipip,
         Wl_t + (l * 3 + 0) * HDIM * HDIM, bl_t + (l * 3 + 0) * HDIM, Wr_t + (l * 3 + 0) * HDIM * HDIM,
         Y_ip, n_ip, 1);
    sage(ccon, ccon, rp_csrc, col_csrc,
         Wl_t + (l * 3 + 1) * HDIM * HDIM, bl_t + (l * 3 + 1) * HDIM, Wr_t + (l * 3 + 1) * HDIM * HDIM,
         Y_con, n_con, 0);
    sage(ccon, ccon, rp_cdst, col_cdst,
         Wl_t + (l * 3 + 2) * HDIM * HDIM, bl_t + (l * 3 + 2) * HDIM, Wr_t + (l * 3 + 2) * HDIM * HDIM,
         Y_con, n_con, 2);
    // spatial heteroconv (reads temporal outputs Y_*)
    sage(Y_ip,  Y_con, rp_ipcon, col_ipcon,
         Wl_s + (l * 2 + 0) * HDIM * HDIM, bl_s + (l * 2 + 0) * HDIM, Wr_s + (l * 2 + 0) * HDIM * HDIM,
         out_con, n_con, 1);
    sage(Y_con, Y_ip,  rp_conip, col_conip,
         Wl_s + (l * 2 + 1) * HDIM * HDIM, bl_s + (l * 2 + 1) * HDIM, Wr_s + (l * 2 + 1) * HDIM * HDIM,
         out_ip, n_ip, 1);
    cip = out_ip;
    ccon = out_con;
  }
}

// Round 5
// 3208.368 us; speedup vs baseline: 1.3878x; 1.3838x over previous
//
#include <hip/hip_runtime.h>

#define HDIM 128
#define NT 32
#define LST 34   // NT + 2: keeps (k*LST + even)*4 8-byte aligned for float2 LDS reads

// ---------------- CSR build kernels ----------------

__global__ void hist_kernel(const int* __restrict__ dst, int* __restrict__ deg, int E) {
  int e = blockIdx.x * 256 + threadIdx.x;
  if (e < E) atomicAdd(&deg[dst[e]], 1);
}

__global__ void scan_block_sum(const int* __restrict__ deg, int* __restrict__ partials, int n) {
  __shared__ int red[256];
  int t = threadIdx.x;
  int base = blockIdx.x * 4096;
  int s = 0;
  #pragma unroll
  for (int i = 0; i < 16; ++i) {
    int idx = base + t + i * 256;
    if (idx < n) s += deg[idx];
  }
  red[t] = s;
  __syncthreads();
  for (int o = 128; o > 0; o >>= 1) {
    if (t < o) red[t] += red[t + o];
    __syncthreads();
  }
  if (t == 0) partials[blockIdx.x] = red[0];
}

__global__ void scan_partials_kernel(int* __restrict__ partials, int* __restrict__ rowptr,
                                     int nb, int n) {
  // single thread: nb <= 49
  int run = 0;
  for (int i = 0; i < nb; ++i) { int v = partials[i]; partials[i] = run; run += v; }
  rowptr[n] = run;
}

__global__ void scan_within(int* __restrict__ deg_cursor, const int* __restrict__ partials,
                            int* __restrict__ rowptr, int n) {
  __shared__ int buf[4096];
  __shared__ int wsum[4];
  int t = threadIdx.x;
  int base = blockIdx.x * 4096;
  #pragma unroll
  for (int i = 0; i < 16; ++i) {
    int idx = base + t + i * 256;
    buf[t + i * 256] = (idx < n) ? deg_cursor[idx] : 0;
  }
  __syncthreads();
  int ex[16];
  int s = 0;
  #pragma unroll
  for (int i = 0; i < 16; ++i) { ex[i] = s; s += buf[t * 16 + i]; }
  int lane = t & 63, w = t >> 6;
  int v = s;
  #pragma unroll
  for (int o = 1; o < 64; o <<= 1) {
    int u = __shfl_up(v, o);
    if (lane >= o) v += u;
  }
  if (lane == 63) wsum[w] = v;
  __syncthreads();
  int off = partials[blockIdx.x] + (v - s);
  for (int i = 0; i < w; ++i) off += wsum[i];
  #pragma unroll
  for (int i = 0; i < 16; ++i) {
    int idx = base + t * 16 + i;
    if (idx < n) { int val = off + ex[i]; rowptr[idx] = val; deg_cursor[idx] = val; }
  }
}

__global__ void scatter_kernel(const int* __restrict__ src, const int* __restrict__ dst,
                               int* __restrict__ cursor, int* __restrict__ col, int E) {
  int e = blockIdx.x * 256 + threadIdx.x;
  if (e < E) {
    int p = atomicAdd(&cursor[dst[e]], 1);
    col[p] = src[e];
  }
}

// ---------------- fused SAGE kernel ----------------
// mode: 0 = write norm (no lrelu), 1 = write lrelu(norm), 2 = out = lrelu(out + norm)

__device__ __forceinline__ void write_row(float* __restrict__ out, int node, int j0,
                                          const float (&acc)[8], float inv, int mode) {
  float o[8];
  #pragma unroll
  for (int b = 0; b < 8; ++b) o[b] = acc[b] * inv;
  float* p = out + node * HDIM + j0;
  if (mode == 2) {
    float4 p0 = *(const float4*)&p[0];
    float4 p1 = *(const float4*)&p[4];
    float prev[8] = {p0.x, p0.y, p0.z, p0.w, p1.x, p1.y, p1.z, p1.w};
    #pragma unroll
    for (int b = 0; b < 8; ++b) {
      float v = o[b] + prev[b];
      o[b] = (v >= 0.f) ? v : 0.01f * v;
    }
  } else if (mode == 1) {
    #pragma unroll
    for (int b = 0; b < 8; ++b) o[b] = (o[b] >= 0.f) ? o[b] : 0.01f * o[b];
  }
  float4 q0 = {o[0], o[1], o[2], o[3]};
  float4 q1 = {o[4], o[5], o[6], o[7]};
  *(float4*)&p[0] = q0;
  *(float4*)&p[4] = q1;
}

__global__ __launch_bounds__(256) void sage_kernel(
    const float* __restrict__ xsrc, const float* __restrict__ xdst,
    const int* __restrict__ rowptr, const int* __restrict__ colidx,
    const float* __restrict__ Wl, const float* __restrict__ bl, const float* __restrict__ Wr,
    float* __restrict__ out, int n_dst, int mode)
{
  __shared__ float lds_a[HDIM * LST];   // agg, [feature][node]
  __shared__ float lds_x[HDIM * LST];   // xdst, [feature][node]
  __shared__ float lds_red[NT * 16];

  int tid = threadIdx.x;
  int n0 = blockIdx.x * NT;

  // ---- phase 1 (parallel): 32 nodes x 8 lanes; each lane owns 16 contiguous feats ----
  // Critical path per thread = deg dependent edge iterations (avg ~2), not 16 serial nodes.
  {
    int ni = tid >> 3;        // 0..31 node within tile
    int c  = tid & 7;         // feature chunk
    int f0 = c * 16;
    int node = n0 + ni;
    float a[16], xr[16];
    #pragma unroll
    for (int j = 0; j < 16; ++j) { a[j] = 0.f; xr[j] = 0.f; }
    if (node < n_dst) {
      const float* xd = &xdst[(size_t)node * HDIM + f0];
      float4 t0 = *(const float4*)(xd + 0);
      float4 t1 = *(const float4*)(xd + 4);
      float4 t2 = *(const float4*)(xd + 8);
      float4 t3 = *(const float4*)(xd + 12);
      xr[0]=t0.x; xr[1]=t0.y; xr[2]=t0.z; xr[3]=t0.w;
      xr[4]=t1.x; xr[5]=t1.y; xr[6]=t1.z; xr[7]=t1.w;
      xr[8]=t2.x; xr[9]=t2.y; xr[10]=t2.z; xr[11]=t2.w;
      xr[12]=t3.x; xr[13]=t3.y; xr[14]=t3.z; xr[15]=t3.w;
      int beg = rowptr[node];
      int end = rowptr[node + 1];
      for (int e = beg; e < end; ++e) {
        const float* xs = &xsrc[(size_t)colidx[e] * HDIM + f0];
        float4 s0 = *(const float4*)(xs + 0);
        float4 s1 = *(const float4*)(xs + 4);
        float4 s2 = *(const float4*)(xs + 8);
        float4 s3 = *(const float4*)(xs + 12);
        a[0]+=s0.x; a[1]+=s0.y; a[2]+=s0.z; a[3]+=s0.w;
        a[4]+=s1.x; a[5]+=s1.y; a[6]+=s1.z; a[7]+=s1.w;
        a[8]+=s2.x; a[9]+=s2.y; a[10]+=s2.z; a[11]+=s2.w;
        a[12]+=s3.x; a[13]+=s3.y; a[14]+=s3.z; a[15]+=s3.w;
      }
      int dg = end - beg;
      if (dg > 0) {
        float inv = 1.0f / (float)dg;
        #pragma unroll
        for (int j = 0; j < 16; ++j) a[j] *= inv;
      }
    }
    // transposed LDS store: [feature][node], stride LST
    #pragma unroll
    for (int j = 0; j < 16; ++j) {
      lds_a[(f0 + j) * LST + ni] = a[j];
      lds_x[(f0 + j) * LST + ni] = xr[j];
    }
  }
  __syncthreads();

  // ---- phase 2: register-tiled GEMM: out = agg@Wl + bl + xd@Wr ----
  int jg = tid & 15;   // feature group: j0..j0+7, adjacent lanes -> adjacent feats (coalesced)
  int ng = tid >> 4;   // node group: nodes na, na+1
  int j0 = jg * 8, na = ng * 2;

  float acc0[8], acc1[8];
  {
    float4 b0 = *(const float4*)&bl[j0];
    float4 b1 = *(const float4*)&bl[j0 + 4];
    float bb[8] = {b0.x, b0.y, b0.z, b0.w, b1.x, b1.y, b1.z, b1.w};
    #pragma unroll
    for (int b = 0; b < 8; ++b) { acc0[b] = bb[b]; acc1[b] = bb[b]; }
  }

  const float* wlp = Wl + j0;
  const float* wrp = Wr + j0;
  #pragma unroll 4
  for (int k = 0; k < HDIM; ++k) {
    float2 av = *(const float2*)&lds_a[k * LST + na];
    float2 xv = *(const float2*)&lds_x[k * LST + na];
    float4 wl0 = *(const float4*)&wlp[k * HDIM];
    float4 wl1 = *(const float4*)&wlp[k * HDIM + 4];
    float4 wr0 = *(const float4*)&wrp[k * HDIM];
    float4 wr1 = *(const float4*)&wrp[k * HDIM + 4];
    float wl[8] = {wl0.x, wl0.y, wl0.z, wl0.w, wl1.x, wl1.y, wl1.z, wl1.w};
    float wr[8] = {wr0.x, wr0.y, wr0.z, wr0.w, wr1.x, wr1.y, wr1.z, wr1.w};
    #pragma unroll
    for (int b = 0; b < 8; ++b) {
      acc0[b] += av.x * wl[b] + xv.x * wr[b];
      acc1[b] += av.y * wl[b] + xv.y * wr[b];
    }
  }

  // ---- phase 3: row norms via LDS reduction, normalize, write ----
  float ss0 = 0.f, ss1 = 0.f;
  #pragma unroll
  for (int b = 0; b < 8; ++b) { ss0 += acc0[b] * acc0[b]; ss1 += acc1[b] * acc1[b]; }
  lds_red[na * 16 + jg] = ss0;
  lds_red[(na + 1) * 16 + jg] = ss1;
  __syncthreads();
  float nrm0 = 0.f, nrm1 = 0.f;
  #pragma unroll
  for (int i = 0; i < 16; ++i) {
    nrm0 += lds_red[na * 16 + i];
    nrm1 += lds_red[(na + 1) * 16 + i];
  }
  float inv0 = 1.0f / fmaxf(sqrtf(nrm0), 1e-12f);
  float inv1 = 1.0f / fmaxf(sqrtf(nrm1), 1e-12f);

  int node0 = n0 + na;
  int node1 = node0 + 1;
  if (node0 < n_dst) write_row(out, node0, j0, acc0, inv0, mode);
  if (node1 < n_dst) write_row(out, node1, j0, acc1, inv1, mode);
}

// ---------------- host launch ----------------

extern "C" void kernel_launch(void* const* d_in, const int* in_sizes, int n_in,
                              void* d_out, int out_size, void* d_ws, size_t ws_size,
                              hipStream_t stream) {
  (void)n_in; (void)out_size; (void)ws_size;
  const float* x_ip  = (const float*)d_in[0];
  const float* x_con = (const float*)d_in[1];
  const int* src_ipcon = (const int*)d_in[2];
  const int* dst_ipcon = (const int*)d_in[3];
  const int* src_conip = (const int*)d_in[4];
  const int* dst_conip = (const int*)d_in[5];
  const int* src_ipip  = (const int*)d_in[6];
  const int* dst_ipip  = (const int*)d_in[7];
  const int* src_csrc  = (const int*)d_in[8];
  const int* dst_csrc  = (const int*)d_in[9];
  const int* src_cdst  = (const int*)d_in[10];
  const int* dst_cdst  = (const int*)d_in[11];
  const float* Wl_t = (const float*)d_in[12];
  const float* bl_t = (const float*)d_in[13];
  const float* Wr_t = (const float*)d_in[14];
  const float* Wl_s = (const float*)d_in[15];
  const float* bl_s = (const float*)d_in[16];
  const float* Wr_s = (const float*)d_in[17];

  const int n_ip  = in_sizes[0] / HDIM;
  const int n_con = in_sizes[1] / HDIM;
  const int E_ipcon = in_sizes[2];
  const int E_conip = in_sizes[4];
  const int E_ipip  = in_sizes[6];
  const int E_csrc  = in_sizes[8];
  const int E_cdst  = in_sizes[10];

  char* ws = (char*)d_ws;
  size_t off = 0;
  auto alloc = [&](size_t bytes) -> void* {
    off = (off + 255) & ~(size_t)255;
    void* p = ws + off;
    off += bytes;
    return p;
  };
  float* Y_ip  = (float*)alloc((size_t)n_ip * HDIM * 4);
  float* Y_con = (float*)alloc((size_t)n_con * HDIM * 4);
  int* cur_all = (int*)alloc((size_t)(2 * n_ip + 3 * n_con) * 4);
  int* cur_ipip  = cur_all;
  int* cur_csrc  = cur_ipip + n_ip;
  int* cur_cdst  = cur_csrc + n_con;
  int* cur_ipcon = cur_cdst + n_con;
  int* cur_conip = cur_ipcon + n_con;
  int* rp_ipip  = (int*)alloc((size_t)(n_ip + 1) * 4);
  int* rp_csrc  = (int*)alloc((size_t)(n_con + 1) * 4);
  int* rp_cdst  = (int*)alloc((size_t)(n_con + 1) * 4);
  int* rp_ipcon = (int*)alloc((size_t)(n_con + 1) * 4);
  int* rp_conip = (int*)alloc((size_t)(n_ip + 1) * 4);
  int* col_ipip  = (int*)alloc((size_t)E_ipip * 4);
  int* col_csrc  = (int*)alloc((size_t)E_csrc * 4);
  int* col_cdst  = (int*)alloc((size_t)E_cdst * 4);
  int* col_ipcon = (int*)alloc((size_t)E_ipcon * 4);
  int* col_conip = (int*)alloc((size_t)E_conip * 4);
  int* partials  = (int*)alloc(256 * 4);

  hipMemsetAsync(cur_all, 0, (size_t)(2 * n_ip + 3 * n_con) * 4, stream);

  auto build = [&](const int* src, const int* dst, int E, int n, int* cur, int* rp, int* col) {
    hist_kernel<<<(E + 255) / 256, 256, 0, stream>>>(dst, cur, E);
    int nb = (n + 4095) / 4096;
    scan_block_sum<<<nb, 256, 0, stream>>>(cur, partials, n);
    scan_partials_kernel<<<1, 1, 0, stream>>>(partials, rp, nb, n);
    scan_within<<<nb, 256, 0, stream>>>(cur, partials, rp, n);
    scatter_kernel<<<(E + 255) / 256, 256, 0, stream>>>(src, dst, cur, col, E);
  };
  build(src_ipip,  dst_ipip,  E_ipip,  n_ip,  cur_ipip,  rp_ipip,  col_ipip);
  build(src_csrc,  dst_csrc,  E_csrc,  n_con, cur_csrc,  rp_csrc,  col_csrc);
  build(src_cdst,  dst_cdst,  E_cdst,  n_con, cur_cdst,  rp_cdst,  col_cdst);
  build(src_ipcon, dst_ipcon, E_ipcon, n_con, cur_ipcon, rp_ipcon, col_ipcon);
  build(src_conip, dst_conip, E_conip, n_ip,  cur_conip, rp_conip, col_conip);

  float* out_ip  = (float*)d_out;
  float* out_con = (float*)d_out + (size_t)n_ip * HDIM;

  auto sage = [&](const float* xs, const float* xd, const int* rp, const int* col,
                  const float* Wl, const float* bl, const float* Wr,
                  float* o, int n, int mode) {
    sage_kernel<<<(n + NT - 1) / NT, 256, 0, stream>>>(xs, xd, rp, col, Wl, bl, Wr, o, n, mode);
  };

  const float* cip  = x_ip;
  const float* ccon = x_con;
  for (int l = 0; l < 2; ++l) {
    // temporal heteroconv
    sage(cip,  cip,  rp_ipip, col_ipip,
         Wl_t + (l * 3 + 0) * HDIM * HDIM, bl_t + (l * 3 + 0) * HDIM, Wr_t + (l * 3 + 0) * HDIM * HDIM,
         Y_ip, n_ip, 1);
    sage(ccon, ccon, rp_csrc, col_csrc,
         Wl_t + (l * 3 + 1) * HDIM * HDIM, bl_t + (l * 3 + 1) * HDIM, Wr_t + (l * 3 + 1) * HDIM * HDIM,
         Y_con, n_con, 0);
    sage(ccon, ccon, rp_cdst, col_cdst,
         Wl_t + (l * 3 + 2) * HDIM * HDIM, bl_t + (l * 3 + 2) * HDIM, Wr_t + (l * 3 + 2) * HDIM * HDIM,
         Y_con, n_con, 2);
    // spatial heteroconv (reads temporal outputs Y_*)
    sage(Y_ip,  Y_con, rp_ipcon, col_ipcon,
         Wl_s + (l * 2 + 0) * HDIM * HDIM, bl_s + (l * 2 + 0) * HDIM, Wr_s + (l * 2 + 0) * HDIM * HDIM,
         out_con, n_con, 1);
    sage(Y_con, Y_ip,  rp_conip, col_conip,
         Wl_s + (l * 2 + 1) * HDIM * HDIM, bl_s + (l * 2 + 1) * HDIM, Wr_s + (l * 2 + 1) * HDIM * HDIM,
         out_ip, n_ip, 1);
    cip = out_ip;
    ccon = out_con;
  }
}

// Round 6
// 994.015 us; speedup vs baseline: 4.4795x; 3.2277x over previous
//
#include <hip/hip_runtime.h>

#define HDIM 128
#define NT 32

typedef __attribute__((ext_vector_type(8))) __bf16 bf16x8;
typedef __attribute__((ext_vector_type(4))) float f32x4;
typedef unsigned short ushort_t;

__device__ __forceinline__ unsigned short f2bf(float f) {
  union { float f; unsigned u; } v; v.f = f;
  unsigned u = v.u;
  return (unsigned short)((u + 0x7FFFu + ((u >> 16) & 1u)) >> 16);
}

// ---------------- CSR build kernels ----------------

__global__ void hist_kernel(const int* __restrict__ dst, int* __restrict__ deg, int E) {
  int e = blockIdx.x * 256 + threadIdx.x;
  if (e < E) atomicAdd(&deg[dst[e]], 1);
}

__global__ void scan_block_sum(const int* __restrict__ deg, int* __restrict__ partials, int n) {
  __shared__ int red[256];
  int t = threadIdx.x;
  int base = blockIdx.x * 4096;
  int s = 0;
  #pragma unroll
  for (int i = 0; i < 16; ++i) {
    int idx = base + t + i * 256;
    if (idx < n) s += deg[idx];
  }
  red[t] = s;
  __syncthreads();
  for (int o = 128; o > 0; o >>= 1) {
    if (t < o) red[t] += red[t + o];
    __syncthreads();
  }
  if (t == 0) partials[blockIdx.x] = red[0];
}

__global__ void scan_partials_kernel(int* __restrict__ partials, int* __restrict__ rowptr,
                                     int nb, int n) {
  int run = 0;
  for (int i = 0; i < nb; ++i) { int v = partials[i]; partials[i] = run; run += v; }
  rowptr[n] = run;
}

__global__ void scan_within(int* __restrict__ deg_cursor, const int* __restrict__ partials,
                            int* __restrict__ rowptr, int n) {
  __shared__ int buf[4096];
  __shared__ int wsum[4];
  int t = threadIdx.x;
  int base = blockIdx.x * 4096;
  #pragma unroll
  for (int i = 0; i < 16; ++i) {
    int idx = base + t + i * 256;
    buf[t + i * 256] = (idx < n) ? deg_cursor[idx] : 0;
  }
  __syncthreads();
  int ex[16];
  int s = 0;
  #pragma unroll
  for (int i = 0; i < 16; ++i) { ex[i] = s; s += buf[t * 16 + i]; }
  int lane = t & 63, w = t >> 6;
  int v = s;
  #pragma unroll
  for (int o = 1; o < 64; o <<= 1) {
    int u = __shfl_up(v, o);
    if (lane >= o) v += u;
  }
  if (lane == 63) wsum[w] = v;
  __syncthreads();
  int off = partials[blockIdx.x] + (v - s);
  for (int i = 0; i < w; ++i) off += wsum[i];
  #pragma unroll
  for (int i = 0; i < 16; ++i) {
    int idx = base + t * 16 + i;
    if (idx < n) { int val = off + ex[i]; rowptr[idx] = val; deg_cursor[idx] = val; }
  }
}

__global__ void scatter_kernel(const int* __restrict__ src, const int* __restrict__ dst,
                               int* __restrict__ cursor, int* __restrict__ col, int E) {
  int e = blockIdx.x * 256 + threadIdx.x;
  if (e < E) {
    int p = atomicAdd(&cursor[dst[e]], 1);
    col[p] = src[e];
  }
}

// ---------------- weight pack (fp32 row-major -> bf16 MFMA B-fragment order) ----
// B-frag for mfma_f32_16x16x32_bf16: lane l holds B[kt*32 + (l>>4)*8 + i][nt*16 + (l&15)],
// i = 0..7, stored contiguously: pack[((kt*8 + nt)*64 + l)*8 + i].

__global__ void pack_w_kernel(const float* __restrict__ W, ushort_t* __restrict__ out, int nmat) {
  int gid = blockIdx.x * 256 + threadIdx.x;
  if (gid >= nmat * 2048) return;
  int lane = gid & 63;
  int nt   = (gid >> 6) & 7;
  int kt   = (gid >> 9) & 3;
  int mat  = gid >> 11;
  const float* w = W + (size_t)mat * HDIM * HDIM;
  ushort_t* o = out + (size_t)mat * HDIM * HDIM + (size_t)(((kt * 8 + nt) * 64 + lane)) * 8;
  int kbase = kt * 32 + (lane >> 4) * 8;
  int n = nt * 16 + (lane & 15);
  #pragma unroll
  for (int i = 0; i < 8; ++i) o[i] = f2bf(w[(size_t)(kbase + i) * HDIM + n]);
}

// ---------------- fused SAGE kernel (bf16 MFMA) ----------------
// mode: 0 = write norm, 1 = write lrelu(norm), 2 = out = lrelu(out + norm)

__global__ __launch_bounds__(256, 4) void sage_mfma_kernel(
    const float* __restrict__ xsrc, const float* __restrict__ xdst,
    const int* __restrict__ rowptr, const int* __restrict__ colidx,
    const ushort_t* __restrict__ pWl, const float* __restrict__ bl,
    const ushort_t* __restrict__ pWr,
    float* __restrict__ out, int n_dst, int mode)
{
  __shared__ ushort_t lds_a[NT * HDIM] __attribute__((aligned(16)));  // agg, bf16, XOR-swizzled
  __shared__ ushort_t lds_x[NT * HDIM] __attribute__((aligned(16)));  // xdst, bf16, XOR-swizzled
  __shared__ float lds_nrm[NT][2];

  int tid = threadIdx.x;
  int n0 = blockIdx.x * NT;

  // ---- phase 1: parallel gather-mean (fp32 accum), bf16 convert, swizzled LDS store ----
  {
    int ni = tid >> 3;        // node within tile 0..31
    int c  = tid & 7;         // 16-feature chunk
    int f0 = c * 16;
    int node = n0 + ni;
    float a[16], xr[16];
    #pragma unroll
    for (int j = 0; j < 16; ++j) { a[j] = 0.f; xr[j] = 0.f; }
    if (node < n_dst) {
      const float* xd = &xdst[(size_t)node * HDIM + f0];
      float4 t0 = *(const float4*)(xd + 0);
      float4 t1 = *(const float4*)(xd + 4);
      float4 t2 = *(const float4*)(xd + 8);
      float4 t3 = *(const float4*)(xd + 12);
      xr[0]=t0.x; xr[1]=t0.y; xr[2]=t0.z; xr[3]=t0.w;
      xr[4]=t1.x; xr[5]=t1.y; xr[6]=t1.z; xr[7]=t1.w;
      xr[8]=t2.x; xr[9]=t2.y; xr[10]=t2.z; xr[11]=t2.w;
      xr[12]=t3.x; xr[13]=t3.y; xr[14]=t3.z; xr[15]=t3.w;
      int beg = rowptr[node];
      int end = rowptr[node + 1];
      for (int e = beg; e < end; ++e) {
        const float* xs = &xsrc[(size_t)colidx[e] * HDIM + f0];
        float4 s0 = *(const float4*)(xs + 0);
        float4 s1 = *(const float4*)(xs + 4);
        float4 s2 = *(const float4*)(xs + 8);
        float4 s3 = *(const float4*)(xs + 12);
        a[0]+=s0.x; a[1]+=s0.y; a[2]+=s0.z; a[3]+=s0.w;
        a[4]+=s1.x; a[5]+=s1.y; a[6]+=s1.z; a[7]+=s1.w;
        a[8]+=s2.x; a[9]+=s2.y; a[10]+=s2.z; a[11]+=s2.w;
        a[12]+=s3.x; a[13]+=s3.y; a[14]+=s3.z; a[15]+=s3.w;
      }
      int dg = end - beg;
      if (dg > 0) {
        float inv = 1.0f / (float)dg;
        #pragma unroll
        for (int j = 0; j < 16; ++j) a[j] *= inv;
      }
    }
    unsigned short ha[16], hx[16];
    #pragma unroll
    for (int j = 0; j < 16; ++j) { ha[j] = f2bf(a[j]); hx[j] = f2bf(xr[j]); }
    uint4 ua0 = { (unsigned)ha[0] | ((unsigned)ha[1]<<16), (unsigned)ha[2] | ((unsigned)ha[3]<<16),
                  (unsigned)ha[4] | ((unsigned)ha[5]<<16), (unsigned)ha[6] | ((unsigned)ha[7]<<16) };
    uint4 ua1 = { (unsigned)ha[8] | ((unsigned)ha[9]<<16), (unsigned)ha[10] | ((unsigned)ha[11]<<16),
                  (unsigned)ha[12] | ((unsigned)ha[13]<<16), (unsigned)ha[14] | ((unsigned)ha[15]<<16) };
    uint4 ux0 = { (unsigned)hx[0] | ((unsigned)hx[1]<<16), (unsigned)hx[2] | ((unsigned)hx[3]<<16),
                  (unsigned)hx[4] | ((unsigned)hx[5]<<16), (unsigned)hx[6] | ((unsigned)hx[7]<<16) };
    uint4 ux1 = { (unsigned)hx[8] | ((unsigned)hx[9]<<16), (unsigned)hx[10] | ((unsigned)hx[11]<<16),
                  (unsigned)hx[12] | ((unsigned)hx[13]<<16), (unsigned)hx[14] | ((unsigned)hx[15]<<16) };
    unsigned sw = (unsigned)(ni & 7) << 4;
    unsigned b0 = (unsigned)(ni * 256 + c * 32);
    *(uint4*)((char*)lds_a + ((b0     ) ^ sw)) = ua0;
    *(uint4*)((char*)lds_a + ((b0 + 16) ^ sw)) = ua1;
    *(uint4*)((char*)lds_x + ((b0     ) ^ sw)) = ux0;
    *(uint4*)((char*)lds_x + ((b0 + 16) ^ sw)) = ux1;
  }
  __syncthreads();

  // ---- phase 2: MFMA GEMM. Wave w: rows m0..m0+15, cols colbase..colbase+63 ----
  int lane = tid & 63, wid = tid >> 6;
  int m0 = (wid & 1) * 16;
  int colbase = (wid >> 1) * 64;
  int lg = lane >> 4, ln = lane & 15;

  // A-fragments: lane holds agg[m0+ln][kt*32 + lg*8 + i]
  bf16x8 aag[4], axx[4];
  {
    int row = m0 + ln;
    unsigned rsw = (unsigned)(row & 7) << 4;
    #pragma unroll
    for (int kt = 0; kt < 4; ++kt) {
      unsigned byt = ((unsigned)(row * 256 + kt * 64 + lg * 16)) ^ rsw;
      aag[kt] = *(const bf16x8*)((const char*)lds_a + byt);
      axx[kt] = *(const bf16x8*)((const char*)lds_x + byt);
    }
  }

  f32x4 acc[4];
  #pragma unroll
  for (int t = 0; t < 4; ++t) {
    float blv = bl[colbase + t * 16 + ln];
    acc[t] = (f32x4){blv, blv, blv, blv};
  }

  #pragma unroll
  for (int t = 0; t < 4; ++t) {
    int ntg = (colbase >> 4) + t;
    #pragma unroll
    for (int kt = 0; kt < 4; ++kt) {
      size_t boff = (size_t)(((kt * 8 + ntg) * 64 + lane)) * 8;
      bf16x8 bwl = *(const bf16x8*)(pWl + boff);
      bf16x8 bwr = *(const bf16x8*)(pWr + boff);
      acc[t] = __builtin_amdgcn_mfma_f32_16x16x32_bf16(aag[kt], bwl, acc[t], 0, 0, 0);
      acc[t] = __builtin_amdgcn_mfma_f32_16x16x32_bf16(axx[kt], bwr, acc[t], 0, 0, 0);
    }
  }

  // ---- phase 3: row L2-norm (shfl over 16 n-lanes + cross-wave LDS), epilogue ----
  float ss[4];
  #pragma unroll
  for (int r = 0; r < 4; ++r) {
    ss[r] = acc[0][r]*acc[0][r] + acc[1][r]*acc[1][r] + acc[2][r]*acc[2][r] + acc[3][r]*acc[3][r];
    ss[r] += __shfl_xor(ss[r], 1);
    ss[r] += __shfl_xor(ss[r], 2);
    ss[r] += __shfl_xor(ss[r], 4);
    ss[r] += __shfl_xor(ss[r], 8);
  }
  if (ln == 0) {
    #pragma unroll
    for (int r = 0; r < 4; ++r) lds_nrm[m0 + lg * 4 + r][wid >> 1] = ss[r];
  }
  __syncthreads();

  #pragma unroll
  for (int r = 0; r < 4; ++r) {
    int m = m0 + lg * 4 + r;
    int node = n0 + m;
    float tot = lds_nrm[m][0] + lds_nrm[m][1];
    float inv = 1.0f / fmaxf(sqrtf(tot), 1e-12f);
    if (node < n_dst) {
      #pragma unroll
      for (int t = 0; t < 4; ++t) {
        int col = colbase + t * 16 + ln;
        float v = acc[t][r] * inv;
        float* po = &out[(size_t)node * HDIM + col];
        if (mode == 2) v += *po;
        if (mode != 0) v = (v >= 0.f) ? v : 0.01f * v;
        *po = v;
      }
    }
  }
}

// ---------------- host launch ----------------

extern "C" void kernel_launch(void* const* d_in, const int* in_sizes, int n_in,
                              void* d_out, int out_size, void* d_ws, size_t ws_size,
                              hipStream_t stream) {
  (void)n_in; (void)out_size; (void)ws_size;
  const float* x_ip  = (const float*)d_in[0];
  const float* x_con = (const float*)d_in[1];
  const int* src_ipcon = (const int*)d_in[2];
  const int* dst_ipcon = (const int*)d_in[3];
  const int* src_conip = (const int*)d_in[4];
  const int* dst_conip = (const int*)d_in[5];
  const int* src_ipip  = (const int*)d_in[6];
  const int* dst_ipip  = (const int*)d_in[7];
  const int* src_csrc  = (const int*)d_in[8];
  const int* dst_csrc  = (const int*)d_in[9];
  const int* src_cdst  = (const int*)d_in[10];
  const int* dst_cdst  = (const int*)d_in[11];
  const float* Wl_t = (const float*)d_in[12];
  const float* bl_t = (const float*)d_in[13];
  const float* Wr_t = (const float*)d_in[14];
  const float* Wl_s = (const float*)d_in[15];
  const float* bl_s = (const float*)d_in[16];
  const float* Wr_s = (const float*)d_in[17];

  const int n_ip  = in_sizes[0] / HDIM;
  const int n_con = in_sizes[1] / HDIM;
  const int E_ipcon = in_sizes[2];
  const int E_conip = in_sizes[4];
  const int E_ipip  = in_sizes[6];
  const int E_csrc  = in_sizes[8];
  const int E_cdst  = in_sizes[10];
  const int MSZ = HDIM * HDIM;   // elements per matrix

  char* ws = (char*)d_ws;
  size_t off = 0;
  auto alloc = [&](size_t bytes) -> void* {
    off = (off + 255) & ~(size_t)255;
    void* p = ws + off;
    off += bytes;
    return p;
  };
  float* Y_ip  = (float*)alloc((size_t)n_ip * HDIM * 4);
  float* Y_con = (float*)alloc((size_t)n_con * HDIM * 4);
  int* cur_all = (int*)alloc((size_t)(2 * n_ip + 3 * n_con) * 4);
  int* cur_ipip  = cur_all;
  int* cur_csrc  = cur_ipip + n_ip;
  int* cur_cdst  = cur_csrc + n_con;
  int* cur_ipcon = cur_cdst + n_con;
  int* cur_conip = cur_ipcon + n_con;
  int* rp_ipip  = (int*)alloc((size_t)(n_ip + 1) * 4);
  int* rp_csrc  = (int*)alloc((size_t)(n_con + 1) * 4);
  int* rp_cdst  = (int*)alloc((size_t)(n_con + 1) * 4);
  int* rp_ipcon = (int*)alloc((size_t)(n_con + 1) * 4);
  int* rp_conip = (int*)alloc((size_t)(n_ip + 1) * 4);
  int* col_ipip  = (int*)alloc((size_t)E_ipip * 4);
  int* col_csrc  = (int*)alloc((size_t)E_csrc * 4);
  int* col_cdst  = (int*)alloc((size_t)E_cdst * 4);
  int* col_ipcon = (int*)alloc((size_t)E_ipcon * 4);
  int* col_conip = (int*)alloc((size_t)E_conip * 4);
  int* partials  = (int*)alloc(256 * 4);
  ushort_t* pWl_t = (ushort_t*)alloc((size_t)6 * MSZ * 2);
  ushort_t* pWr_t = (ushort_t*)alloc((size_t)6 * MSZ * 2);
  ushort_t* pWl_s = (ushort_t*)alloc((size_t)4 * MSZ * 2);
  ushort_t* pWr_s = (ushort_t*)alloc((size_t)4 * MSZ * 2);

  hipMemsetAsync(cur_all, 0, (size_t)(2 * n_ip + 3 * n_con) * 4, stream);

  // pack all 20 weight matrices to bf16 MFMA fragment order
  pack_w_kernel<<<(6 * 2048 + 255) / 256, 256, 0, stream>>>(Wl_t, pWl_t, 6);
  pack_w_kernel<<<(6 * 2048 + 255) / 256, 256, 0, stream>>>(Wr_t, pWr_t, 6);
  pack_w_kernel<<<(4 * 2048 + 255) / 256, 256, 0, stream>>>(Wl_s, pWl_s, 4);
  pack_w_kernel<<<(4 * 2048 + 255) / 256, 256, 0, stream>>>(Wr_s, pWr_s, 4);

  auto build = [&](const int* src, const int* dst, int E, int n, int* cur, int* rp, int* col) {
    hist_kernel<<<(E + 255) / 256, 256, 0, stream>>>(dst, cur, E);
    int nb = (n + 4095) / 4096;
    scan_block_sum<<<nb, 256, 0, stream>>>(cur, partials, n);
    scan_partials_kernel<<<1, 1, 0, stream>>>(partials, rp, nb, n);
    scan_within<<<nb, 256, 0, stream>>>(cur, partials, rp, n);
    scatter_kernel<<<(E + 255) / 256, 256, 0, stream>>>(src, dst, cur, col, E);
  };
  build(src_ipip,  dst_ipip,  E_ipip,  n_ip,  cur_ipip,  rp_ipip,  col_ipip);
  build(src_csrc,  dst_csrc,  E_csrc,  n_con, cur_csrc,  rp_csrc,  col_csrc);
  build(src_cdst,  dst_cdst,  E_cdst,  n_con, cur_cdst,  rp_cdst,  col_cdst);
  build(src_ipcon, dst_ipcon, E_ipcon, n_con, cur_ipcon, rp_ipcon, col_ipcon);
  build(src_conip, dst_conip, E_conip, n_ip,  cur_conip, rp_conip, col_conip);

  float* out_ip  = (float*)d_out;
  float* out_con = (float*)d_out + (size_t)n_ip * HDIM;

  auto sage = [&](const float* xs, const float* xd, const int* rp, const int* col,
                  const ushort_t* pWl, const float* bl, const ushort_t* pWr,
                  float* o, int n, int mode) {
    sage_mfma_kernel<<<(n + NT - 1) / NT, 256, 0, stream>>>(xs, xd, rp, col, pWl, bl, pWr, o, n, mode);
  };

  const float* cip  = x_ip;
  const float* ccon = x_con;
  for (int l = 0; l < 2; ++l) {
    // temporal heteroconv
    sage(cip,  cip,  rp_ipip, col_ipip,
         pWl_t + (size_t)(l * 3 + 0) * MSZ, bl_t + (l * 3 + 0) * HDIM, pWr_t + (size_t)(l * 3 + 0) * MSZ,
         Y_ip, n_ip, 1);
    sage(ccon, ccon, rp_csrc, col_csrc,
         pWl_t + (size_t)(l * 3 + 1) * MSZ, bl_t + (l * 3 + 1) * HDIM, pWr_t + (size_t)(l * 3 + 1) * MSZ,
         Y_con, n_con, 0);
    sage(ccon, ccon, rp_cdst, col_cdst,
         pWl_t + (size_t)(l * 3 + 2) * MSZ, bl_t + (l * 3 + 2) * HDIM, pWr_t + (size_t)(l * 3 + 2) * MSZ,
         Y_con, n_con, 2);
    // spatial heteroconv (reads temporal outputs Y_*)
    sage(Y_ip,  Y_con, rp_ipcon, col_ipcon,
         pWl_s + (size_t)(l * 2 + 0) * MSZ, bl_s + (l * 2 + 0) * HDIM, pWr_s + (size_t)(l * 2 + 0) * MSZ,
         out_con, n_con, 1);
    sage(Y_con, Y_ip,  rp_conip, col_conip,
         pWl_s + (size_t)(l * 2 + 1) * MSZ, bl_s + (l * 2 + 1) * HDIM, pWr_s + (size_t)(l * 2 + 1) * MSZ,
         out_ip, n_ip, 1);
    cip = out_ip;
    ccon = out_con;
  }
}

// Round 8
// 843.580 us; speedup vs baseline: 5.2783x; 1.1783x over previous
//
#include <hip/hip_runtime.h>

#define HDIM 128
#define NT 32
#define MSZ (HDIM * HDIM)

typedef __attribute__((ext_vector_type(8))) __bf16 bf16x8;
typedef __attribute__((ext_vector_type(4))) float f32x4;
typedef unsigned short ushort_t;

__device__ __forceinline__ unsigned short f2bf(float f) {
  union { float f; unsigned u; } v; v.f = f;
  unsigned u = v.u;
  return (unsigned short)((u + 0x7FFFu + ((u >> 16) & 1u)) >> 16);
}

// ---------------- combined CSR build ----------------
// Single node domain: [ipip(n_ip) | csrc(n_con) | cdst(n_con) | ipcon(n_con) | conip(n_ip)]
// Single edge domain in the same order. One rowptr (Ntot+1) + one col array (Etot).

struct BuildArgs {
  const int* src0; const int* dst0;
  const int* src1; const int* dst1;
  const int* src2; const int* dst2;
  const int* src3; const int* dst3;
  const int* src4; const int* dst4;
  int eb1, eb2, eb3, eb4, eb5;   // edge prefix boundaries
  int no0, no1, no2, no3, no4;   // node-domain offsets
};

__device__ __forceinline__ void resolve(const BuildArgs& a, int gid,
                                        const int*& sp, const int*& dp, int& base, int& no) {
  sp = a.src0; dp = a.dst0; base = 0; no = a.no0;
  if (gid >= a.eb1) { sp = a.src1; dp = a.dst1; base = a.eb1; no = a.no1; }
  if (gid >= a.eb2) { sp = a.src2; dp = a.dst2; base = a.eb2; no = a.no2; }
  if (gid >= a.eb3) { sp = a.src3; dp = a.dst3; base = a.eb3; no = a.no3; }
  if (gid >= a.eb4) { sp = a.src4; dp = a.dst4; base = a.eb4; no = a.no4; }
}

__global__ void hist_all_kernel(BuildArgs a, int* __restrict__ deg) {
  int gid = blockIdx.x * 256 + threadIdx.x;
  if (gid >= a.eb5) return;
  const int *sp, *dp; int base, no;
  resolve(a, gid, sp, dp, base, no);
  atomicAdd(&deg[no + dp[gid - base]], 1);
}

__global__ void scatter_all_kernel(BuildArgs a, int* __restrict__ cursor, int* __restrict__ col) {
  int gid = blockIdx.x * 256 + threadIdx.x;
  if (gid >= a.eb5) return;
  const int *sp, *dp; int base, no;
  resolve(a, gid, sp, dp, base, no);
  int e = gid - base;
  int p = atomicAdd(&cursor[no + dp[e]], 1);
  col[p] = sp[e];
}

__global__ void scan_block_sum(const int* __restrict__ deg, int* __restrict__ partials, int n) {
  __shared__ int red[256];
  int t = threadIdx.x;
  int base = blockIdx.x * 4096;
  int s = 0;
  #pragma unroll
  for (int i = 0; i < 16; ++i) {
    int idx = base + t + i * 256;
    if (idx < n) s += deg[idx];
  }
  red[t] = s;
  __syncthreads();
  for (int o = 128; o > 0; o >>= 1) {
    if (t < o) red[t] += red[t + o];
    __syncthreads();
  }
  if (t == 0) partials[blockIdx.x] = red[0];
}

__global__ void scan_partials_kernel(int* __restrict__ partials, int* __restrict__ rowptr,
                                     int nb, int n) {
  int run = 0;
  for (int i = 0; i < nb; ++i) { int v = partials[i]; partials[i] = run; run += v; }
  rowptr[n] = run;
}

__global__ void scan_within(int* __restrict__ deg_cursor, const int* __restrict__ partials,
                            int* __restrict__ rowptr, int n) {
  __shared__ int buf[4096];
  __shared__ int wsum[4];
  int t = threadIdx.x;
  int base = blockIdx.x * 4096;
  #pragma unroll
  for (int i = 0; i < 16; ++i) {
    int idx = base + t + i * 256;
    buf[t + i * 256] = (idx < n) ? deg_cursor[idx] : 0;
  }
  __syncthreads();
  int ex[16];
  int s = 0;
  #pragma unroll
  for (int i = 0; i < 16; ++i) { ex[i] = s; s += buf[t * 16 + i]; }
  int lane = t & 63, w = t >> 6;
  int v = s;
  #pragma unroll
  for (int o = 1; o < 64; o <<= 1) {
    int u = __shfl_up(v, o);
    if (lane >= o) v += u;
  }
  if (lane == 63) wsum[w] = v;
  __syncthreads();
  int off = partials[blockIdx.x] + (v - s);
  for (int i = 0; i < w; ++i) off += wsum[i];
  #pragma unroll
  for (int i = 0; i < 16; ++i) {
    int idx = base + t * 16 + i;
    if (idx < n) { int val = off + ex[i]; rowptr[idx] = val; deg_cursor[idx] = val; }
  }
}

// ---------------- weight pack: all 20 matrices -> bf16 MFMA B-fragment order ----
// pack layout per matrix: frag[((kt*8 + nt)*64 + lane)*8 + i] = W[kt*32+(lane>>4)*8+i][nt*16+(lane&15)]
// combined matrix order: [Wl_t(6) | Wr_t(6) | Wl_s(4) | Wr_s(4)]

__global__ void pack_all_kernel(const float* __restrict__ Wl_t, const float* __restrict__ Wr_t,
                                const float* __restrict__ Wl_s, const float* __restrict__ Wr_s,
                                ushort_t* __restrict__ out) {
  int gid = blockIdx.x * 256 + threadIdx.x;
  if (gid >= 20 * 2048) return;
  int lane = gid & 63;
  int nt   = (gid >> 6) & 7;
  int kt   = (gid >> 9) & 3;
  int mat  = gid >> 11;
  const float* w;
  if (mat < 6)       w = Wl_t + (size_t)mat * MSZ;
  else if (mat < 12) w = Wr_t + (size_t)(mat - 6) * MSZ;
  else if (mat < 16) w = Wl_s + (size_t)(mat - 12) * MSZ;
  else               w = Wr_s + (size_t)(mat - 16) * MSZ;
  ushort_t* o = out + (size_t)mat * MSZ + (size_t)(((kt * 8 + nt) * 64 + lane)) * 8;
  int kbase = kt * 32 + (lane >> 4) * 8;
  int n = nt * 16 + (lane & 15);
  #pragma unroll
  for (int i = 0; i < 8; ++i) o[i] = f2bf(w[(size_t)(kbase + i) * HDIM + n]);
}

// ---------------- gather helper: mean-aggregate one (node, 16-feat chunk) ----

__device__ __forceinline__ void gather_mean(const float* __restrict__ xsrc,
                                            const int* __restrict__ rowptr,
                                            const int* __restrict__ colidx,
                                            int node, int f0, float (&a)[16]) {
  #pragma unroll
  for (int j = 0; j < 16; ++j) a[j] = 0.f;
  int beg = rowptr[node];
  int end = rowptr[node + 1];
  for (int e = beg; e < end; ++e) {
    const float* xs = &xsrc[(size_t)colidx[e] * HDIM + f0];
    float4 s0 = *(const float4*)(xs + 0);
    float4 s1 = *(const float4*)(xs + 4);
    float4 s2 = *(const float4*)(xs + 8);
    float4 s3 = *(const float4*)(xs + 12);
    a[0]+=s0.x; a[1]+=s0.y; a[2]+=s0.z; a[3]+=s0.w;
    a[4]+=s1.x; a[5]+=s1.y; a[6]+=s1.z; a[7]+=s1.w;
    a[8]+=s2.x; a[9]+=s2.y; a[10]+=s2.z; a[11]+=s2.w;
    a[12]+=s3.x; a[13]+=s3.y; a[14]+=s3.z; a[15]+=s3.w;
  }
  int dg = end - beg;
  if (dg > 0) {
    float inv = 1.0f / (float)dg;
    #pragma unroll
    for (int j = 0; j < 16; ++j) a[j] *= inv;
  }
}

__device__ __forceinline__ void store_tile16(ushort_t* __restrict__ tile, int ni, int c,
                                             const float (&a)[16]) {
  unsigned short h[16];
  #pragma unroll
  for (int j = 0; j < 16; ++j) h[j] = f2bf(a[j]);
  uint4 u0 = { (unsigned)h[0] | ((unsigned)h[1]<<16), (unsigned)h[2] | ((unsigned)h[3]<<16),
               (unsigned)h[4] | ((unsigned)h[5]<<16), (unsigned)h[6] | ((unsigned)h[7]<<16) };
  uint4 u1 = { (unsigned)h[8] | ((unsigned)h[9]<<16), (unsigned)h[10] | ((unsigned)h[11]<<16),
               (unsigned)h[12] | ((unsigned)h[13]<<16), (unsigned)h[14] | ((unsigned)h[15]<<16) };
  unsigned sw = (unsigned)(ni & 7) << 4;
  unsigned b0 = (unsigned)(ni * 256 + c * 32);
  *(uint4*)((char*)tile + ((b0     ) ^ sw)) = u0;
  *(uint4*)((char*)tile + ((b0 + 16) ^ sw)) = u1;
}

// ---------------- simple SAGE block (always: write lrelu(normalized)) ----------------

__device__ __forceinline__ void sage_simple_block(
    int n0, int n_dst,
    const float* __restrict__ xsrc, const float* __restrict__ xdst,
    const int* __restrict__ rowptr, const int* __restrict__ colidx,
    const ushort_t* __restrict__ pWl, const float* __restrict__ bl,
    const ushort_t* __restrict__ pWr,
    float* __restrict__ out,
    ushort_t* __restrict__ lds_a, ushort_t* __restrict__ lds_x, float (*lds_nrm)[4],
    int tid)
{
  // phase 1
  {
    int ni = tid >> 3, c = tid & 7, f0 = c * 16;
    int node = n0 + ni;
    float a[16], xr[16];
    #pragma unroll
    for (int j = 0; j < 16; ++j) { a[j] = 0.f; xr[j] = 0.f; }
    if (node < n_dst) {
      const float* xd = &xdst[(size_t)node * HDIM + f0];
      float4 t0 = *(const float4*)(xd + 0);
      float4 t1 = *(const float4*)(xd + 4);
      float4 t2 = *(const float4*)(xd + 8);
      float4 t3 = *(const float4*)(xd + 12);
      xr[0]=t0.x; xr[1]=t0.y; xr[2]=t0.z; xr[3]=t0.w;
      xr[4]=t1.x; xr[5]=t1.y; xr[6]=t1.z; xr[7]=t1.w;
      xr[8]=t2.x; xr[9]=t2.y; xr[10]=t2.z; xr[11]=t2.w;
      xr[12]=t3.x; xr[13]=t3.y; xr[14]=t3.z; xr[15]=t3.w;
      gather_mean(xsrc, rowptr, colidx, node, f0, a);
    }
    store_tile16(lds_a, ni, c, a);
    store_tile16(lds_x, ni, c, xr);
  }
  __syncthreads();

  // phase 2
  int lane = tid & 63, wid = tid >> 6;
  int m0 = (wid & 1) * 16;
  int colbase = (wid >> 1) * 64;
  int lg = lane >> 4, ln = lane & 15;

  bf16x8 aag[4], axx[4];
  {
    int row = m0 + ln;
    unsigned rsw = (unsigned)(row & 7) << 4;
    #pragma unroll
    for (int kt = 0; kt < 4; ++kt) {
      unsigned byt = ((unsigned)(row * 256 + kt * 64 + lg * 16)) ^ rsw;
      aag[kt] = *(const bf16x8*)((const char*)lds_a + byt);
      axx[kt] = *(const bf16x8*)((const char*)lds_x + byt);
    }
  }

  f32x4 acc[4];
  #pragma unroll
  for (int t = 0; t < 4; ++t) {
    float blv = bl[colbase + t * 16 + ln];
    acc[t] = (f32x4){blv, blv, blv, blv};
  }

  #pragma unroll
  for (int t = 0; t < 4; ++t) {
    int ntg = (colbase >> 4) + t;
    #pragma unroll
    for (int kt = 0; kt < 4; ++kt) {
      size_t boff = (size_t)(((kt * 8 + ntg) * 64 + lane)) * 8;
      bf16x8 bwl = *(const bf16x8*)(pWl + boff);
      bf16x8 bwr = *(const bf16x8*)(pWr + boff);
      acc[t] = __builtin_amdgcn_mfma_f32_16x16x32_bf16(aag[kt], bwl, acc[t], 0, 0, 0);
      acc[t] = __builtin_amdgcn_mfma_f32_16x16x32_bf16(axx[kt], bwr, acc[t], 0, 0, 0);
    }
  }

  // phase 3
  float ss[4];
  #pragma unroll
  for (int r = 0; r < 4; ++r) {
    ss[r] = acc[0][r]*acc[0][r] + acc[1][r]*acc[1][r] + acc[2][r]*acc[2][r] + acc[3][r]*acc[3][r];
    ss[r] += __shfl_xor(ss[r], 1);
    ss[r] += __shfl_xor(ss[r], 2);
    ss[r] += __shfl_xor(ss[r], 4);
    ss[r] += __shfl_xor(ss[r], 8);
  }
  if (ln == 0) {
    #pragma unroll
    for (int r = 0; r < 4; ++r) lds_nrm[m0 + lg * 4 + r][wid >> 1] = ss[r];
  }
  __syncthreads();

  #pragma unroll
  for (int r = 0; r < 4; ++r) {
    int m = m0 + lg * 4 + r;
    int node = n0 + m;
    float tot = lds_nrm[m][0] + lds_nrm[m][1];
    float inv = 1.0f / fmaxf(sqrtf(tot), 1e-12f);
    if (node < n_dst) {
      #pragma unroll
      for (int t = 0; t < 4; ++t) {
        int col = colbase + t * 16 + ln;
        float v = acc[t][r] * inv;
        v = (v >= 0.f) ? v : 0.01f * v;
        out[(size_t)node * HDIM + col] = v;
      }
    }
  }
}

// ---------------- temporal combo: fused con (csrc+cdst) blocks + ipip blocks ----------------

__global__ __launch_bounds__(256, 4) void temporal_kernel(
    const float* __restrict__ x_ip, const float* __restrict__ x_con,
    const int* __restrict__ rp_ipip, const int* __restrict__ rp_csrc, const int* __restrict__ rp_cdst,
    const int* __restrict__ col_all,
    const ushort_t* __restrict__ pWl_ip, const float* __restrict__ bl_ip, const ushort_t* __restrict__ pWr_ip,
    const ushort_t* __restrict__ pWl_c1, const float* __restrict__ bl_c1, const ushort_t* __restrict__ pWr_c1,
    const ushort_t* __restrict__ pWl_c2, const float* __restrict__ bl_c2, const ushort_t* __restrict__ pWr_c2,
    float* __restrict__ Y_ip, float* __restrict__ Y_con,
    int n_ip, int n_con, int nb_con)
{
  __shared__ ushort_t lds[3 * NT * HDIM] __attribute__((aligned(16)));
  __shared__ float lds_nrm[NT][4];
  int tid = threadIdx.x;

  if ((int)blockIdx.x >= nb_con) {
    // ---- ipip simple block ----
    int n0 = ((int)blockIdx.x - nb_con) * NT;
    sage_simple_block(n0, n_ip, x_ip, x_ip, rp_ipip, col_all,
                      pWl_ip, bl_ip, pWr_ip, Y_ip,
                      lds, lds + NT * HDIM, lds_nrm, tid);
    return;
  }

  // ---- fused con block: Y_con = lrelu(norm(agg1@Wl1+bl1+x@Wr1) + norm(agg2@Wl2+bl2+x@Wr2)) ----
  int n0 = (int)blockIdx.x * NT;
  ushort_t* lds_x  = lds;
  ushort_t* lds_a1 = lds + NT * HDIM;
  ushort_t* lds_a2 = lds + 2 * NT * HDIM;

  {
    int ni = tid >> 3, c = tid & 7, f0 = c * 16;
    int node = n0 + ni;
    float a[16];
    if (node < n_con) {
      const float* xd = &x_con[(size_t)node * HDIM + f0];
      float4 t0 = *(const float4*)(xd + 0);
      float4 t1 = *(const float4*)(xd + 4);
      float4 t2 = *(const float4*)(xd + 8);
      float4 t3 = *(const float4*)(xd + 12);
      a[0]=t0.x; a[1]=t0.y; a[2]=t0.z; a[3]=t0.w;
      a[4]=t1.x; a[5]=t1.y; a[6]=t1.z; a[7]=t1.w;
      a[8]=t2.x; a[9]=t2.y; a[10]=t2.z; a[11]=t2.w;
      a[12]=t3.x; a[13]=t3.y; a[14]=t3.z; a[15]=t3.w;
    } else {
      #pragma unroll
      for (int j = 0; j < 16; ++j) a[j] = 0.f;
    }
    store_tile16(lds_x, ni, c, a);
    if (node < n_con) gather_mean(x_con, rp_csrc, col_all, node, f0, a);
    else { for (int j = 0; j < 16; ++j) a[j] = 0.f; }
    store_tile16(lds_a1, ni, c, a);
    if (node < n_con) gather_mean(x_con, rp_cdst, col_all, node, f0, a);
    else { for (int j = 0; j < 16; ++j) a[j] = 0.f; }
    store_tile16(lds_a2, ni, c, a);
  }
  __syncthreads();

  int lane = tid & 63, wid = tid >> 6;
  int m0 = (wid & 1) * 16;
  int colbase = (wid >> 1) * 64;
  int lg = lane >> 4, ln = lane & 15;
  int row = m0 + ln;
  unsigned rsw = (unsigned)(row & 7) << 4;
  unsigned byt[4];
  #pragma unroll
  for (int kt = 0; kt < 4; ++kt)
    byt[kt] = ((unsigned)(row * 256 + kt * 64 + lg * 16)) ^ rsw;

  bf16x8 axx[4], afr[4];
  #pragma unroll
  for (int kt = 0; kt < 4; ++kt) axx[kt] = *(const bf16x8*)((const char*)lds_x + byt[kt]);

  f32x4 acc1[4], acc2[4];
  #pragma unroll
  for (int t = 0; t < 4; ++t) {
    float b1 = bl_c1[colbase + t * 16 + ln];
    float b2 = bl_c2[colbase + t * 16 + ln];
    acc1[t] = (f32x4){b1, b1, b1, b1};
    acc2[t] = (f32x4){b2, b2, b2, b2};
  }

  // pass 1: branch csrc  (acc1 = a1@Wl1 + x@Wr1)
  #pragma unroll
  for (int kt = 0; kt < 4; ++kt) afr[kt] = *(const bf16x8*)((const char*)lds_a1 + byt[kt]);
  #pragma unroll
  for (int t = 0; t < 4; ++t) {
    int ntg = (colbase >> 4) + t;
    #pragma unroll
    for (int kt = 0; kt < 4; ++kt) {
      size_t boff = (size_t)(((kt * 8 + ntg) * 64 + lane)) * 8;
      bf16x8 bwl = *(const bf16x8*)(pWl_c1 + boff);
      bf16x8 bwr = *(const bf16x8*)(pWr_c1 + boff);
      acc1[t] = __builtin_amdgcn_mfma_f32_16x16x32_bf16(afr[kt], bwl, acc1[t], 0, 0, 0);
      acc1[t] = __builtin_amdgcn_mfma_f32_16x16x32_bf16(axx[kt], bwr, acc1[t], 0, 0, 0);
    }
  }
  // pass 2: branch cdst  (acc2 = a2@Wl2 + x@Wr2)
  #pragma unroll
  for (int kt = 0; kt < 4; ++kt) afr[kt] = *(const bf16x8*)((const char*)lds_a2 + byt[kt]);
  #pragma unroll
  for (int t = 0; t < 4; ++t) {
    int ntg = (colbase >> 4) + t;
    #pragma unroll
    for (int kt = 0; kt < 4; ++kt) {
      size_t boff = (size_t)(((kt * 8 + ntg) * 64 + lane)) * 8;
      bf16x8 bwl = *(const bf16x8*)(pWl_c2 + boff);
      bf16x8 bwr = *(const bf16x8*)(pWr_c2 + boff);
      acc2[t] = __builtin_amdgcn_mfma_f32_16x16x32_bf16(afr[kt], bwl, acc2[t], 0, 0, 0);
      acc2[t] = __builtin_amdgcn_mfma_f32_16x16x32_bf16(axx[kt], bwr, acc2[t], 0, 0, 0);
    }
  }

  // norms for both branches
  float ss1[4], ss2[4];
  #pragma unroll
  for (int r = 0; r < 4; ++r) {
    ss1[r] = acc1[0][r]*acc1[0][r] + acc1[1][r]*acc1[1][r] + acc1[2][r]*acc1[2][r] + acc1[3][r]*acc1[3][r];
    ss2[r] = acc2[0][r]*acc2[0][r] + acc2[1][r]*acc2[1][r] + acc2[2][r]*acc2[2][r] + acc2[3][r]*acc2[3][r];
    #pragma unroll
    for (int o = 1; o < 16; o <<= 1) {
      ss1[r] += __shfl_xor(ss1[r], o);
      ss2[r] += __shfl_xor(ss2[r], o);
    }
  }
  if (ln == 0) {
    #pragma unroll
    for (int r = 0; r < 4; ++r) {
      lds_nrm[m0 + lg * 4 + r][(wid >> 1)]     = ss1[r];
      lds_nrm[m0 + lg * 4 + r][2 + (wid >> 1)] = ss2[r];
    }
  }
  __syncthreads();

  #pragma unroll
  for (int r = 0; r < 4; ++r) {
    int m = m0 + lg * 4 + r;
    int node = n0 + m;
    float inv1 = 1.0f / fmaxf(sqrtf(lds_nrm[m][0] + lds_nrm[m][1]), 1e-12f);
    float inv2 = 1.0f / fmaxf(sqrtf(lds_nrm[m][2] + lds_nrm[m][3]), 1e-12f);
    if (node < n_con) {
      #pragma unroll
      for (int t = 0; t < 4; ++t) {
        int col = colbase + t * 16 + ln;
        float v = acc1[t][r] * inv1 + acc2[t][r] * inv2;
        v = (v >= 0.f) ? v : 0.01f * v;
        Y_con[(size_t)node * HDIM + col] = v;
      }
    }
  }
}

// ---------------- spatial combo: ipcon blocks + conip blocks ----------------

__global__ __launch_bounds__(256, 8) void spatial_kernel(
    const float* __restrict__ Y_ip, const float* __restrict__ Y_con,
    const int* __restrict__ rp_ipcon, const int* __restrict__ rp_conip,
    const int* __restrict__ col_all,
    const ushort_t* __restrict__ pWl_ic, const float* __restrict__ bl_ic, const ushort_t* __restrict__ pWr_ic,
    const ushort_t* __restrict__ pWl_ci, const float* __restrict__ bl_ci, const ushort_t* __restrict__ pWr_ci,
    float* __restrict__ out_ip, float* __restrict__ out_con,
    int n_ip, int n_con, int nb_con)
{
  __shared__ ushort_t lds[2 * NT * HDIM] __attribute__((aligned(16)));
  __shared__ float lds_nrm[NT][4];
  int tid = threadIdx.x;

  if ((int)blockIdx.x < nb_con) {
    int n0 = (int)blockIdx.x * NT;
    sage_simple_block(n0, n_con, Y_ip, Y_con, rp_ipcon, col_all,
                      pWl_ic, bl_ic, pWr_ic, out_con,
                      lds, lds + NT * HDIM, lds_nrm, tid);
  } else {
    int n0 = ((int)blockIdx.x - nb_con) * NT;
    sage_simple_block(n0, n_ip, Y_con, Y_ip, rp_conip, col_all,
                      pWl_ci, bl_ci, pWr_ci, out_ip,
                      lds, lds + NT * HDIM, lds_nrm, tid);
  }
}

// ---------------- host launch ----------------

extern "C" void kernel_launch(void* const* d_in, const int* in_sizes, int n_in,
                              void* d_out, int out_size, void* d_ws, size_t ws_size,
                              hipStream_t stream) {
  (void)n_in; (void)out_size; (void)ws_size;
  const float* x_ip  = (const float*)d_in[0];
  const float* x_con = (const float*)d_in[1];
  const int* src_ipcon = (const int*)d_in[2];
  const int* dst_ipcon = (const int*)d_in[3];
  const int* src_conip = (const int*)d_in[4];
  const int* dst_conip = (const int*)d_in[5];
  const int* src_ipip  = (const int*)d_in[6];
  const int* dst_ipip  = (const int*)d_in[7];
  const int* src_csrc  = (const int*)d_in[8];
  const int* dst_csrc  = (const int*)d_in[9];
  const int* src_cdst  = (const int*)d_in[10];
  const int* dst_cdst  = (const int*)d_in[11];
  const float* Wl_t = (const float*)d_in[12];
  const float* bl_t = (const float*)d_in[13];
  const float* Wr_t = (const float*)d_in[14];
  const float* Wl_s = (const float*)d_in[15];
  const float* bl_s = (const float*)d_in[16];
  const float* Wr_s = (const float*)d_in[17];

  const int n_ip  = in_sizes[0] / HDIM;
  const int n_con = in_sizes[1] / HDIM;
  const int E_ipcon = in_sizes[2];
  const int E_conip = in_sizes[4];
  const int E_ipip  = in_sizes[6];
  const int E_csrc  = in_sizes[8];
  const int E_cdst  = in_sizes[10];

  // combined domains: node order [ipip | csrc | cdst | ipcon | conip]
  const int no_ipip  = 0;
  const int no_csrc  = n_ip;
  const int no_cdst  = n_ip + n_con;
  const int no_ipcon = n_ip + 2 * n_con;
  const int no_conip = n_ip + 3 * n_con;
  const int Ntot = 2 * n_ip + 3 * n_con;
  const int eb1 = E_ipip;
  const int eb2 = eb1 + E_csrc;
  const int eb3 = eb2 + E_cdst;
  const int eb4 = eb3 + E_ipcon;
  const int Etot = eb4 + E_conip;

  char* ws = (char*)d_ws;
  size_t off = 0;
  auto alloc = [&](size_t bytes) -> void* {
    off = (off + 255) & ~(size_t)255;
    void* p = ws + off;
    off += bytes;
    return p;
  };
  float* Y_ip  = (float*)alloc((size_t)n_ip * HDIM * 4);
  float* Y_con = (float*)alloc((size_t)n_con * HDIM * 4);
  int* cur_all = (int*)alloc((size_t)Ntot * 4);
  int* rp_all  = (int*)alloc((size_t)(Ntot + 1) * 4);
  int* col_all = (int*)alloc((size_t)Etot * 4);
  int* partials = (int*)alloc(256 * 4);
  ushort_t* pW = (ushort_t*)alloc((size_t)20 * MSZ * 2);

  (void)hipMemsetAsync(cur_all, 0, (size_t)Ntot * 4, stream);

  BuildArgs ba;
  ba.src0 = src_ipip;  ba.dst0 = dst_ipip;
  ba.src1 = src_csrc;  ba.dst1 = dst_csrc;
  ba.src2 = src_cdst;  ba.dst2 = dst_cdst;
  ba.src3 = src_ipcon; ba.dst3 = dst_ipcon;
  ba.src4 = src_conip; ba.dst4 = dst_conip;
  ba.eb1 = eb1; ba.eb2 = eb2; ba.eb3 = eb3; ba.eb4 = eb4; ba.eb5 = Etot;
  ba.no0 = no_ipip; ba.no1 = no_csrc; ba.no2 = no_cdst; ba.no3 = no_ipcon; ba.no4 = no_conip;

  pack_all_kernel<<<(20 * 2048 + 255) / 256, 256, 0, stream>>>(Wl_t, Wr_t, Wl_s, Wr_s, pW);
  hist_all_kernel<<<(Etot + 255) / 256, 256, 0, stream>>>(ba, cur_all);
  int nb = (Ntot + 4095) / 4096;
  scan_block_sum<<<nb, 256, 0, stream>>>(cur_all, partials, Ntot);
  scan_partials_kernel<<<1, 1, 0, stream>>>(partials, rp_all, nb, Ntot);
  scan_within<<<nb, 256, 0, stream>>>(cur_all, partials, rp_all, Ntot);
  scatter_all_kernel<<<(Etot + 255) / 256, 256, 0, stream>>>(ba, cur_all, col_all);

  float* out_ip  = (float*)d_out;
  float* out_con = (float*)d_out + (size_t)n_ip * HDIM;

  const int nb_con = (n_con + NT - 1) / NT;
  const int nb_ip  = (n_ip + NT - 1) / NT;

  const float* cip  = x_ip;
  const float* ccon = x_con;
  for (int l = 0; l < 2; ++l) {
    const ushort_t* pWl_ip = pW + (size_t)(l * 3 + 0) * MSZ;
    const ushort_t* pWr_ip = pW + (size_t)(6 + l * 3 + 0) * MSZ;
    const ushort_t* pWl_c1 = pW + (size_t)(l * 3 + 1) * MSZ;
    const ushort_t* pWr_c1 = pW + (size_t)(6 + l * 3 + 1) * MSZ;
    const ushort_t* pWl_c2 = pW + (size_t)(l * 3 + 2) * MSZ;
    const ushort_t* pWr_c2 = pW + (size_t)(6 + l * 3 + 2) * MSZ;
    temporal_kernel<<<nb_con + nb_ip, 256, 0, stream>>>(
        cip, ccon,
        rp_all + no_ipip, rp_all + no_csrc, rp_all + no_cdst, col_all,
        pWl_ip, bl_t + (l * 3 + 0) * HDIM, pWr_ip,
        pWl_c1, bl_t + (l * 3 + 1) * HDIM, pWr_c1,
        pWl_c2, bl_t + (l * 3 + 2) * HDIM, pWr_c2,
        Y_ip, Y_con, n_ip, n_con, nb_con);

    const ushort_t* pWl_ic = pW + (size_t)(12 + l * 2 + 0) * MSZ;
    const ushort_t* pWr_ic = pW + (size_t)(16 + l * 2 + 0) * MSZ;
    const ushort_t* pWl_ci = pW + (size_t)(12 + l * 2 + 1) * MSZ;
    const ushort_t* pWr_ci = pW + (size_t)(16 + l * 2 + 1) * MSZ;
    spatial_kernel<<<nb_con + nb_ip, 256, 0, stream>>>(
        Y_ip, Y_con,
        rp_all + no_ipcon, rp_all + no_conip, col_all,
        pWl_ic, bl_s + (l * 2 + 0) * HDIM, pWr_ic,
        pWl_ci, bl_s + (l * 2 + 1) * HDIM, pWr_ci,
        out_ip, out_con, n_ip, n_con, nb_con);

    cip = out_ip;
    ccon = out_con;
  }
}

// Round 10
// 687.937 us; speedup vs baseline: 6.4725x; 1.2262x over previous
//
#include <hip/hip_runtime.h>

#define HDIM 128
#define NT 32
#define MSZ (HDIM * HDIM)

typedef _Float16 half_t;
typedef __attribute__((ext_vector_type(8))) _Float16 f16x8;
typedef __attribute__((ext_vector_type(4))) float f32x4;

__device__ __forceinline__ f16x8 f16x8_zero() {
  f16x8 v = {0, 0, 0, 0, 0, 0, 0, 0};
  return v;
}

// ---------------- combined CSR build ----------------
// Node domain: [ipip(n_ip) | csrc(n_con) | cdst(n_con) | ipcon(n_con) | conip(n_ip)]

struct BuildArgs {
  const int* src0; const int* dst0;
  const int* src1; const int* dst1;
  const int* src2; const int* dst2;
  const int* src3; const int* dst3;
  const int* src4; const int* dst4;
  int eb1, eb2, eb3, eb4, eb5;
  int no0, no1, no2, no3, no4;
};

__device__ __forceinline__ void resolve(const BuildArgs& a, int gid,
                                        const int*& sp, const int*& dp, int& base, int& no) {
  sp = a.src0; dp = a.dst0; base = 0; no = a.no0;
  if (gid >= a.eb1) { sp = a.src1; dp = a.dst1; base = a.eb1; no = a.no1; }
  if (gid >= a.eb2) { sp = a.src2; dp = a.dst2; base = a.eb2; no = a.no2; }
  if (gid >= a.eb3) { sp = a.src3; dp = a.dst3; base = a.eb3; no = a.no3; }
  if (gid >= a.eb4) { sp = a.src4; dp = a.dst4; base = a.eb4; no = a.no4; }
}

__global__ void hist_all_kernel(BuildArgs a, int* __restrict__ deg) {
  int gid = blockIdx.x * 256 + threadIdx.x;
  if (gid >= a.eb5) return;
  const int *sp, *dp; int base, no;
  resolve(a, gid, sp, dp, base, no);
  atomicAdd(&deg[no + dp[gid - base]], 1);
}

__global__ void scatter_all_kernel(BuildArgs a, int* __restrict__ cursor, int* __restrict__ col) {
  int gid = blockIdx.x * 256 + threadIdx.x;
  if (gid >= a.eb5) return;
  const int *sp, *dp; int base, no;
  resolve(a, gid, sp, dp, base, no);
  int e = gid - base;
  int p = atomicAdd(&cursor[no + dp[e]], 1);
  col[p] = sp[e];
}

__global__ void scan_block_sum(const int* __restrict__ deg, int* __restrict__ partials, int n) {
  __shared__ int red[256];
  int t = threadIdx.x;
  int base = blockIdx.x * 4096;
  int s = 0;
  #pragma unroll
  for (int i = 0; i < 16; ++i) {
    int idx = base + t + i * 256;
    if (idx < n) s += deg[idx];
  }
  red[t] = s;
  __syncthreads();
  for (int o = 128; o > 0; o >>= 1) {
    if (t < o) red[t] += red[t + o];
    __syncthreads();
  }
  if (t == 0) partials[blockIdx.x] = red[0];
}

__global__ void scan_partials_kernel(int* __restrict__ partials, int* __restrict__ rowptr,
                                     int nb, int n) {
  int run = 0;
  for (int i = 0; i < nb; ++i) { int v = partials[i]; partials[i] = run; run += v; }
  rowptr[n] = run;
}

__global__ void scan_within(int* __restrict__ deg_cursor, const int* __restrict__ partials,
                            int* __restrict__ rowptr, int n) {
  __shared__ int buf[4096];
  __shared__ int wsum[4];
  int t = threadIdx.x;
  int base = blockIdx.x * 4096;
  #pragma unroll
  for (int i = 0; i < 16; ++i) {
    int idx = base + t + i * 256;
    buf[t + i * 256] = (idx < n) ? deg_cursor[idx] : 0;
  }
  __syncthreads();
  int ex[16];
  int s = 0;
  #pragma unroll
  for (int i = 0; i < 16; ++i) { ex[i] = s; s += buf[t * 16 + i]; }
  int lane = t & 63, w = t >> 6;
  int v = s;
  #pragma unroll
  for (int o = 1; o < 64; o <<= 1) {
    int u = __shfl_up(v, o);
    if (lane >= o) v += u;
  }
  if (lane == 63) wsum[w] = v;
  __syncthreads();
  int off = partials[blockIdx.x] + (v - s);
  for (int i = 0; i < w; ++i) off += wsum[i];
  #pragma unroll
  for (int i = 0; i < 16; ++i) {
    int idx = base + t * 16 + i;
    if (idx < n) { int val = off + ex[i]; rowptr[idx] = val; deg_cursor[idx] = val; }
  }
}

// ---------------- fp32 -> f16 input conversion ----------------

__global__ void cvt_f2h_kernel(const float* __restrict__ in, half_t* __restrict__ out, int n8) {
  int i = blockIdx.x * 256 + threadIdx.x;
  if (i >= n8) return;
  const float4* p = (const float4*)(in + (size_t)i * 8);
  float4 a = p[0], b = p[1];
  f16x8 h = { (_Float16)a.x, (_Float16)a.y, (_Float16)a.z, (_Float16)a.w,
              (_Float16)b.x, (_Float16)b.y, (_Float16)b.z, (_Float16)b.w };
  *(f16x8*)(out + (size_t)i * 8) = h;
}

// ---------------- weight pack: fp32 row-major -> f16 MFMA B-fragment order ----
// frag[((kt*8+nt)*64+lane)*8+i] = W[kt*32+(lane>>4)*8+i][nt*16+(lane&15)]
// order: [Wl_t(6) | Wr_t(6) | Wl_s(4) | Wr_s(4)]

__global__ void pack_all_kernel(const float* __restrict__ Wl_t, const float* __restrict__ Wr_t,
                                const float* __restrict__ Wl_s, const float* __restrict__ Wr_s,
                                half_t* __restrict__ out) {
  int gid = blockIdx.x * 256 + threadIdx.x;
  if (gid >= 20 * 2048) return;
  int lane = gid & 63;
  int nt   = (gid >> 6) & 7;
  int kt   = (gid >> 9) & 3;
  int mat  = gid >> 11;
  const float* w;
  if (mat < 6)       w = Wl_t + (size_t)mat * MSZ;
  else if (mat < 12) w = Wr_t + (size_t)(mat - 6) * MSZ;
  else if (mat < 16) w = Wl_s + (size_t)(mat - 12) * MSZ;
  else               w = Wr_s + (size_t)(mat - 16) * MSZ;
  half_t* o = out + (size_t)mat * MSZ + (size_t)(((kt * 8 + nt) * 64 + lane)) * 8;
  int kbase = kt * 32 + (lane >> 4) * 8;
  int n = nt * 16 + (lane & 15);
  #pragma unroll
  for (int i = 0; i < 8; ++i) o[i] = (_Float16)w[(size_t)(kbase + i) * HDIM + n];
}

// ---------------- gather: mean-aggregate, f16 rows, 2-wide edge batching ----

__device__ __forceinline__ void gather_mean_h(const half_t* __restrict__ xsrc,
                                              const int* __restrict__ rowptr,
                                              const int* __restrict__ colidx,
                                              int node, int f0, float (&a)[16]) {
  #pragma unroll
  for (int j = 0; j < 16; ++j) a[j] = 0.f;
  int beg = rowptr[node];
  int end = rowptr[node + 1];
  for (int e = beg; e < end; e += 2) {
    int e1 = (e + 1 < end) ? e + 1 : e;
    float w1 = (e + 1 < end) ? 1.f : 0.f;
    int c0 = colidx[e], c1 = colidx[e1];
    const half_t* r0 = &xsrc[(size_t)c0 * HDIM + f0];
    const half_t* r1 = &xsrc[(size_t)c1 * HDIM + f0];
    f16x8 p0 = *(const f16x8*)r0;
    f16x8 p1 = *(const f16x8*)(r0 + 8);
    f16x8 q0 = *(const f16x8*)r1;
    f16x8 q1 = *(const f16x8*)(r1 + 8);
    #pragma unroll
    for (int j = 0; j < 8; ++j) {
      a[j]     += (float)p0[j] + w1 * (float)q0[j];
      a[j + 8] += (float)p1[j] + w1 * (float)q1[j];
    }
  }
  int dg = end - beg;
  if (dg > 0) {
    float inv = 1.0f / (float)dg;
    #pragma unroll
    for (int j = 0; j < 16; ++j) a[j] *= inv;
  }
}

// swizzled LDS tile store: [node][feat] f16, byte ^= (ni&7)<<4
__device__ __forceinline__ void st_tile_h(half_t* __restrict__ tile, int ni, int c,
                                          f16x8 lo, f16x8 hi) {
  unsigned sw = (unsigned)(ni & 7) << 4;
  unsigned b0 = (unsigned)(ni * 256 + c * 32);
  *(f16x8*)((char*)tile + ((b0     ) ^ sw)) = lo;
  *(f16x8*)((char*)tile + ((b0 + 16) ^ sw)) = hi;
}

__device__ __forceinline__ void st_tile_f(half_t* __restrict__ tile, int ni, int c,
                                          const float (&a)[16]) {
  f16x8 lo, hi;
  #pragma unroll
  for (int j = 0; j < 8; ++j) { lo[j] = (_Float16)a[j]; hi[j] = (_Float16)a[j + 8]; }
  st_tile_h(tile, ni, c, lo, hi);
}

// ---------------- simple SAGE block: out = lrelu(normalize(agg@Wl+bl+x@Wr)) ----
// wf32: 1 -> write fp32 to out_f, 0 -> write f16 to out_h

__device__ __forceinline__ void sage_simple_block(
    int n0, int n_dst,
    const half_t* __restrict__ xsrc, const half_t* __restrict__ xdst,
    const int* __restrict__ rowptr, const int* __restrict__ colidx,
    const half_t* __restrict__ pWl, const float* __restrict__ bl,
    const half_t* __restrict__ pWr,
    half_t* __restrict__ out_h, float* __restrict__ out_f, int wf32,
    half_t* __restrict__ lds_a, half_t* __restrict__ lds_x, float (*lds_nrm)[4],
    int tid)
{
  // phase 1
  {
    int ni = tid >> 3, c = tid & 7, f0 = c * 16;
    int node = n0 + ni;
    f16x8 x0 = f16x8_zero(), x1 = f16x8_zero();
    float a[16];
    #pragma unroll
    for (int j = 0; j < 16; ++j) a[j] = 0.f;
    if (node < n_dst) {
      const half_t* xd = &xdst[(size_t)node * HDIM + f0];
      x0 = *(const f16x8*)xd;
      x1 = *(const f16x8*)(xd + 8);
      gather_mean_h(xsrc, rowptr, colidx, node, f0, a);
    }
    st_tile_h(lds_x, ni, c, x0, x1);
    st_tile_f(lds_a, ni, c, a);
  }
  __syncthreads();

  // phase 2
  int lane = tid & 63, wid = tid >> 6;
  int m0 = (wid & 1) * 16;
  int colbase = (wid >> 1) * 64;
  int lg = lane >> 4, ln = lane & 15;

  f16x8 aag[4], axx[4];
  {
    int row = m0 + ln;
    unsigned rsw = (unsigned)(row & 7) << 4;
    #pragma unroll
    for (int kt = 0; kt < 4; ++kt) {
      unsigned byt = ((unsigned)(row * 256 + kt * 64 + lg * 16)) ^ rsw;
      aag[kt] = *(const f16x8*)((const char*)lds_a + byt);
      axx[kt] = *(const f16x8*)((const char*)lds_x + byt);
    }
  }

  f32x4 acc[4];
  #pragma unroll
  for (int t = 0; t < 4; ++t) {
    float blv = bl[colbase + t * 16 + ln];
    acc[t] = (f32x4){blv, blv, blv, blv};
  }

  #pragma unroll
  for (int t = 0; t < 4; ++t) {
    int ntg = (colbase >> 4) + t;
    #pragma unroll
    for (int kt = 0; kt < 4; ++kt) {
      size_t boff = (size_t)(((kt * 8 + ntg) * 64 + lane)) * 8;
      f16x8 bwl = *(const f16x8*)(pWl + boff);
      f16x8 bwr = *(const f16x8*)(pWr + boff);
      acc[t] = __builtin_amdgcn_mfma_f32_16x16x32_f16(aag[kt], bwl, acc[t], 0, 0, 0);
      acc[t] = __builtin_amdgcn_mfma_f32_16x16x32_f16(axx[kt], bwr, acc[t], 0, 0, 0);
    }
  }

  // phase 3
  float ss[4];
  #pragma unroll
  for (int r = 0; r < 4; ++r) {
    ss[r] = acc[0][r]*acc[0][r] + acc[1][r]*acc[1][r] + acc[2][r]*acc[2][r] + acc[3][r]*acc[3][r];
    ss[r] += __shfl_xor(ss[r], 1);
    ss[r] += __shfl_xor(ss[r], 2);
    ss[r] += __shfl_xor(ss[r], 4);
    ss[r] += __shfl_xor(ss[r], 8);
  }
  if (ln == 0) {
    #pragma unroll
    for (int r = 0; r < 4; ++r) lds_nrm[m0 + lg * 4 + r][wid >> 1] = ss[r];
  }
  __syncthreads();

  #pragma unroll
  for (int r = 0; r < 4; ++r) {
    int m = m0 + lg * 4 + r;
    int node = n0 + m;
    float tot = lds_nrm[m][0] + lds_nrm[m][1];
    float inv = 1.0f / fmaxf(sqrtf(tot), 1e-12f);
    if (node < n_dst) {
      #pragma unroll
      for (int t = 0; t < 4; ++t) {
        int col = colbase + t * 16 + ln;
        float v = acc[t][r] * inv;
        v = (v >= 0.f) ? v : 0.01f * v;
        if (wf32) out_f[(size_t)node * HDIM + col] = v;
        else      out_h[(size_t)node * HDIM + col] = (_Float16)v;
      }
    }
  }
}

// ---------------- temporal combo: fused con (csrc+cdst) + ipip ----------------

__global__ __launch_bounds__(256, 6) void temporal_kernel(
    const half_t* __restrict__ x_ip, const half_t* __restrict__ x_con,
    const int* __restrict__ rp_ipip, const int* __restrict__ rp_csrc, const int* __restrict__ rp_cdst,
    const int* __restrict__ col_all,
    const half_t* __restrict__ pWl_ip, const float* __restrict__ bl_ip, const half_t* __restrict__ pWr_ip,
    const half_t* __restrict__ pWl_c1, const float* __restrict__ bl_c1, const half_t* __restrict__ pWr_c1,
    const half_t* __restrict__ pWl_c2, const float* __restrict__ bl_c2, const half_t* __restrict__ pWr_c2,
    half_t* __restrict__ Y_ip, half_t* __restrict__ Y_con,
    int n_ip, int n_con, int nb_con)
{
  __shared__ half_t lds[3 * NT * HDIM] __attribute__((aligned(16)));
  __shared__ float lds_nrm[NT][4];
  int tid = threadIdx.x;

  if ((int)blockIdx.x >= nb_con) {
    int n0 = ((int)blockIdx.x - nb_con) * NT;
    sage_simple_block(n0, n_ip, x_ip, x_ip, rp_ipip, col_all,
                      pWl_ip, bl_ip, pWr_ip, Y_ip, nullptr, 0,
                      lds, lds + NT * HDIM, lds_nrm, tid);
    return;
  }

  // fused con block: Y_con = lrelu(norm(a1@Wl1+b1+x@Wr1) + norm(a2@Wl2+b2+x@Wr2))
  int n0 = (int)blockIdx.x * NT;
  half_t* lds_x  = lds;
  half_t* lds_a1 = lds + NT * HDIM;
  half_t* lds_a2 = lds + 2 * NT * HDIM;

  {
    int ni = tid >> 3, c = tid & 7, f0 = c * 16;
    int node = n0 + ni;
    f16x8 x0 = f16x8_zero(), x1 = f16x8_zero();
    float a[16];
    #pragma unroll
    for (int j = 0; j < 16; ++j) a[j] = 0.f;
    if (node < n_con) {
      const half_t* xd = &x_con[(size_t)node * HDIM + f0];
      x0 = *(const f16x8*)xd;
      x1 = *(const f16x8*)(xd + 8);
    }
    st_tile_h(lds_x, ni, c, x0, x1);
    if (node < n_con) {
      gather_mean_h(x_con, rp_csrc, col_all, node, f0, a);
    }
    st_tile_f(lds_a1, ni, c, a);
    if (node < n_con) {
      gather_mean_h(x_con, rp_cdst, col_all, node, f0, a);
    } else {
      #pragma unroll
      for (int j = 0; j < 16; ++j) a[j] = 0.f;
    }
    st_tile_f(lds_a2, ni, c, a);
  }
  __syncthreads();

  int lane = tid & 63, wid = tid >> 6;
  int m0 = (wid & 1) * 16;
  int colbase = (wid >> 1) * 64;
  int lg = lane >> 4, ln = lane & 15;
  int row = m0 + ln;
  unsigned rsw = (unsigned)(row & 7) << 4;
  unsigned byt[4];
  #pragma unroll
  for (int kt = 0; kt < 4; ++kt)
    byt[kt] = ((unsigned)(row * 256 + kt * 64 + lg * 16)) ^ rsw;

  f16x8 axx[4], afr[4];
  #pragma unroll
  for (int kt = 0; kt < 4; ++kt) axx[kt] = *(const f16x8*)((const char*)lds_x + byt[kt]);

  f32x4 acc1[4], acc2[4];
  #pragma unroll
  for (int t = 0; t < 4; ++t) {
    float b1 = bl_c1[colbase + t * 16 + ln];
    float b2 = bl_c2[colbase + t * 16 + ln];
    acc1[t] = (f32x4){b1, b1, b1, b1};
    acc2[t] = (f32x4){b2, b2, b2, b2};
  }

  #pragma unroll
  for (int kt = 0; kt < 4; ++kt) afr[kt] = *(const f16x8*)((const char*)lds_a1 + byt[kt]);
  #pragma unroll
  for (int t = 0; t < 4; ++t) {
    int ntg = (colbase >> 4) + t;
    #pragma unroll
    for (int kt = 0; kt < 4; ++kt) {
      size_t boff = (size_t)(((kt * 8 + ntg) * 64 + lane)) * 8;
      f16x8 bwl = *(const f16x8*)(pWl_c1 + boff);
      f16x8 bwr = *(const f16x8*)(pWr_c1 + boff);
      acc1[t] = __builtin_amdgcn_mfma_f32_16x16x32_f16(afr[kt], bwl, acc1[t], 0, 0, 0);
      acc1[t] = __builtin_amdgcn_mfma_f32_16x16x32_f16(axx[kt], bwr, acc1[t], 0, 0, 0);
    }
  }
  #pragma unroll
  for (int kt = 0; kt < 4; ++kt) afr[kt] = *(const f16x8*)((const char*)lds_a2 + byt[kt]);
  #pragma unroll
  for (int t = 0; t < 4; ++t) {
    int ntg = (colbase >> 4) + t;
    #pragma unroll
    for (int kt = 0; kt < 4; ++kt) {
      size_t boff = (size_t)(((kt * 8 + ntg) * 64 + lane)) * 8;
      f16x8 bwl = *(const f16x8*)(pWl_c2 + boff);
      f16x8 bwr = *(const f16x8*)(pWr_c2 + boff);
      acc2[t] = __builtin_amdgcn_mfma_f32_16x16x32_f16(afr[kt], bwl, acc2[t], 0, 0, 0);
      acc2[t] = __builtin_amdgcn_mfma_f32_16x16x32_f16(axx[kt], bwr, acc2[t], 0, 0, 0);
    }
  }

  float ss1[4], ss2[4];
  #pragma unroll
  for (int r = 0; r < 4; ++r) {
    ss1[r] = acc1[0][r]*acc1[0][r] + acc1[1][r]*acc1[1][r] + acc1[2][r]*acc1[2][r] + acc1[3][r]*acc1[3][r];
    ss2[r] = acc2[0][r]*acc2[0][r] + acc2[1][r]*acc2[1][r] + acc2[2][r]*acc2[2][r] + acc2[3][r]*acc2[3][r];
    #pragma unroll
    for (int o = 1; o < 16; o <<= 1) {
      ss1[r] += __shfl_xor(ss1[r], o);
      ss2[r] += __shfl_xor(ss2[r], o);
    }
  }
  if (ln == 0) {
    #pragma unroll
    for (int r = 0; r < 4; ++r) {
      lds_nrm[m0 + lg * 4 + r][(wid >> 1)]     = ss1[r];
      lds_nrm[m0 + lg * 4 + r][2 + (wid >> 1)] = ss2[r];
    }
  }
  __syncthreads();

  #pragma unroll
  for (int r = 0; r < 4; ++r) {
    int m = m0 + lg * 4 + r;
    int node = n0 + m;
    float inv1 = 1.0f / fmaxf(sqrtf(lds_nrm[m][0] + lds_nrm[m][1]), 1e-12f);
    float inv2 = 1.0f / fmaxf(sqrtf(lds_nrm[m][2] + lds_nrm[m][3]), 1e-12f);
    if (node < n_con) {
      #pragma unroll
      for (int t = 0; t < 4; ++t) {
        int col = colbase + t * 16 + ln;
        float v = acc1[t][r] * inv1 + acc2[t][r] * inv2;
        v = (v >= 0.f) ? v : 0.01f * v;
        Y_con[(size_t)node * HDIM + col] = (_Float16)v;
      }
    }
  }
}

// ---------------- spatial combo: ipcon + conip ----------------

__global__ __launch_bounds__(256, 6) void spatial_kernel(
    const half_t* __restrict__ Y_ip, const half_t* __restrict__ Y_con,
    const int* __restrict__ rp_ipcon, const int* __restrict__ rp_conip,
    const int* __restrict__ col_all,
    const half_t* __restrict__ pWl_ic, const float* __restrict__ bl_ic, const half_t* __restrict__ pWr_ic,
    const half_t* __restrict__ pWl_ci, const float* __restrict__ bl_ci, const half_t* __restrict__ pWr_ci,
    half_t* __restrict__ zh_ip, half_t* __restrict__ zh_con,
    float* __restrict__ out_ip, float* __restrict__ out_con,
    int wf32, int n_ip, int n_con, int nb_con)
{
  __shared__ half_t lds[2 * NT * HDIM] __attribute__((aligned(16)));
  __shared__ float lds_nrm[NT][4];
  int tid = threadIdx.x;

  if ((int)blockIdx.x < nb_con) {
    int n0 = (int)blockIdx.x * NT;
    sage_simple_block(n0, n_con, Y_ip, Y_con, rp_ipcon, col_all,
                      pWl_ic, bl_ic, pWr_ic, zh_con, out_con, wf32,
                      lds, lds + NT * HDIM, lds_nrm, tid);
  } else {
    int n0 = ((int)blockIdx.x - nb_con) * NT;
    sage_simple_block(n0, n_ip, Y_con, Y_ip, rp_conip, col_all,
                      pWl_ci, bl_ci, pWr_ci, zh_ip, out_ip, wf32,
                      lds, lds + NT * HDIM, lds_nrm, tid);
  }
}

// ---------------- host launch ----------------

extern "C" void kernel_launch(void* const* d_in, const int* in_sizes, int n_in,
                              void* d_out, int out_size, void* d_ws, size_t ws_size,
                              hipStream_t stream) {
  (void)n_in; (void)out_size; (void)ws_size;
  const float* x_ip  = (const float*)d_in[0];
  const float* x_con = (const float*)d_in[1];
  const int* src_ipcon = (const int*)d_in[2];
  const int* dst_ipcon = (const int*)d_in[3];
  const int* src_conip = (const int*)d_in[4];
  const int* dst_conip = (const int*)d_in[5];
  const int* src_ipip  = (const int*)d_in[6];
  const int* dst_ipip  = (const int*)d_in[7];
  const int* src_csrc  = (const int*)d_in[8];
  const int* dst_csrc  = (const int*)d_in[9];
  const int* src_cdst  = (const int*)d_in[10];
  const int* dst_cdst  = (const int*)d_in[11];
  const float* Wl_t = (const float*)d_in[12];
  const float* bl_t = (const float*)d_in[13];
  const float* Wr_t = (const float*)d_in[14];
  const float* Wl_s = (const float*)d_in[15];
  const float* bl_s = (const float*)d_in[16];
  const float* Wr_s = (const float*)d_in[17];

  const int n_ip  = in_sizes[0] / HDIM;
  const int n_con = in_sizes[1] / HDIM;
  const int E_ipcon = in_sizes[2];
  const int E_conip = in_sizes[4];
  const int E_ipip  = in_sizes[6];
  const int E_csrc  = in_sizes[8];
  const int E_cdst  = in_sizes[10];

  const int no_ipip  = 0;
  const int no_csrc  = n_ip;
  const int no_cdst  = n_ip + n_con;
  const int no_ipcon = n_ip + 2 * n_con;
  const int no_conip = n_ip + 3 * n_con;
  const int Ntot = 2 * n_ip + 3 * n_con;
  const int eb1 = E_ipip;
  const int eb2 = eb1 + E_csrc;
  const int eb3 = eb2 + E_cdst;
  const int eb4 = eb3 + E_ipcon;
  const int Etot = eb4 + E_conip;

  char* ws = (char*)d_ws;
  size_t off = 0;
  auto alloc = [&](size_t bytes) -> void* {
    off = (off + 255) & ~(size_t)255;
    void* p = ws + off;
    off += bytes;
    return p;
  };
  // xh buffers double as spatial outputs (xh dead after the layer's temporal conv)
  half_t* xh_ip  = (half_t*)alloc((size_t)n_ip * HDIM * 2);
  half_t* xh_con = (half_t*)alloc((size_t)n_con * HDIM * 2);
  half_t* Yh_ip  = (half_t*)alloc((size_t)n_ip * HDIM * 2);
  half_t* Yh_con = (half_t*)alloc((size_t)n_con * HDIM * 2);
  int* cur_all = (int*)alloc((size_t)Ntot * 4);
  int* rp_all  = (int*)alloc((size_t)(Ntot + 1) * 4);
  int* col_all = (int*)alloc((size_t)Etot * 4);
  int* partials = (int*)alloc(256 * 4);
  half_t* pW = (half_t*)alloc((size_t)20 * MSZ * 2);

  (void)hipMemsetAsync(cur_all, 0, (size_t)Ntot * 4, stream);

  BuildArgs ba;
  ba.src0 = src_ipip;  ba.dst0 = dst_ipip;
  ba.src1 = src_csrc;  ba.dst1 = dst_csrc;
  ba.src2 = src_cdst;  ba.dst2 = dst_cdst;
  ba.src3 = src_ipcon; ba.dst3 = dst_ipcon;
  ba.src4 = src_conip; ba.dst4 = dst_conip;
  ba.eb1 = eb1; ba.eb2 = eb2; ba.eb3 = eb3; ba.eb4 = eb4; ba.eb5 = Etot;
  ba.no0 = no_ipip; ba.no1 = no_csrc; ba.no2 = no_cdst; ba.no3 = no_ipcon; ba.no4 = no_conip;

  cvt_f2h_kernel<<<(n_ip * HDIM / 8 + 255) / 256, 256, 0, stream>>>(x_ip, xh_ip, n_ip * HDIM / 8);
  cvt_f2h_kernel<<<(n_con * HDIM / 8 + 255) / 256, 256, 0, stream>>>(x_con, xh_con, n_con * HDIM / 8);
  pack_all_kernel<<<(20 * 2048 + 255) / 256, 256, 0, stream>>>(Wl_t, Wr_t, Wl_s, Wr_s, pW);
  hist_all_kernel<<<(Etot + 255) / 256, 256, 0, stream>>>(ba, cur_all);
  int nb = (Ntot + 4095) / 4096;
  scan_block_sum<<<nb, 256, 0, stream>>>(cur_all, partials, Ntot);
  scan_partials_kernel<<<1, 1, 0, stream>>>(partials, rp_all, nb, Ntot);
  scan_within<<<nb, 256, 0, stream>>>(cur_all, partials, rp_all, Ntot);
  scatter_all_kernel<<<(Etot + 255) / 256, 256, 0, stream>>>(ba, cur_all, col_all);

  float* out_ip  = (float*)d_out;
  float* out_con = (float*)d_out + (size_t)n_ip * HDIM;

  const int nb_con = (n_con + NT - 1) / NT;
  const int nb_ip  = (n_ip + NT - 1) / NT;

  const half_t* cip  = xh_ip;
  const half_t* ccon = xh_con;
  for (int l = 0; l < 2; ++l) {
    const half_t* pWl_ip = pW + (size_t)(l * 3 + 0) * MSZ;
    const half_t* pWr_ip = pW + (size_t)(6 + l * 3 + 0) * MSZ;
    const half_t* pWl_c1 = pW + (size_t)(l * 3 + 1) * MSZ;
    const half_t* pWr_c1 = pW + (size_t)(6 + l * 3 + 1) * MSZ;
    const half_t* pWl_c2 = pW + (size_t)(l * 3 + 2) * MSZ;
    const half_t* pWr_c2 = pW + (size_t)(6 + l * 3 + 2) * MSZ;
    temporal_kernel<<<nb_con + nb_ip, 256, 0, stream>>>(
        cip, ccon,
        rp_all + no_ipip, rp_all + no_csrc, rp_all + no_cdst, col_all,
        pWl_ip, bl_t + (l * 3 + 0) * HDIM, pWr_ip,
        pWl_c1, bl_t + (l * 3 + 1) * HDIM, pWr_c1,
        pWl_c2, bl_t + (l * 3 + 2) * HDIM, pWr_c2,
        Yh_ip, Yh_con, n_ip, n_con, nb_con);

    const half_t* pWl_ic = pW + (size_t)(12 + l * 2 + 0) * MSZ;
    const half_t* pWr_ic = pW + (size_t)(16 + l * 2 + 0) * MSZ;
    const half_t* pWl_ci = pW + (size_t)(12 + l * 2 + 1) * MSZ;
    const half_t* pWr_ci = pW + (size_t)(16 + l * 2 + 1) * MSZ;
    spatial_kernel<<<nb_con + nb_ip, 256, 0, stream>>>(
        Yh_ip, Yh_con,
        rp_all + no_ipcon, rp_all + no_conip, col_all,
        pWl_ic, bl_s + (l * 2 + 0) * HDIM, pWr_ic,
        pWl_ci, bl_s + (l * 2 + 1) * HDIM, pWr_ci,
        xh_ip, xh_con, out_ip, out_con, (l == 1) ? 1 : 0,
        n_ip, n_con, nb_con);

    cip = xh_ip;
    ccon = xh_con;
  }
}

// Round 11
// 650.759 us; speedup vs baseline: 6.8423x; 1.0571x over previous
//
#include <hip/hip_runtime.h>

#define HDIM 128
#define NT 32
#define MSZ (HDIM * HDIM)
#define NBLK 512        // blocks for bucket passes
#define MAXNB 1024      // max buckets (Ntot < 1M nodes)
#define BSH 10          // bucket = global_node >> BSH

typedef _Float16 half_t;
typedef __attribute__((ext_vector_type(8))) _Float16 f16x8;
typedef __attribute__((ext_vector_type(4))) float f32x4;

__device__ __forceinline__ f16x8 f16x8_zero() {
  f16x8 v = {0, 0, 0, 0, 0, 0, 0, 0};
  return v;
}

// ---------------- combined edge domain ----------------
// Node domain: [ipip(n_ip) | csrc(n_con) | cdst(n_con) | ipcon(n_con) | conip(n_ip)]

struct BuildArgs {
  const int* src0; const int* dst0;
  const int* src1; const int* dst1;
  const int* src2; const int* dst2;
  const int* src3; const int* dst3;
  const int* src4; const int* dst4;
  int eb1, eb2, eb3, eb4, eb5;
  int no0, no1, no2, no3, no4;
};

__device__ __forceinline__ void resolve(const BuildArgs& a, int gid,
                                        const int*& sp, const int*& dp, int& base, int& no) {
  sp = a.src0; dp = a.dst0; base = 0; no = a.no0;
  if (gid >= a.eb1) { sp = a.src1; dp = a.dst1; base = a.eb1; no = a.no1; }
  if (gid >= a.eb2) { sp = a.src2; dp = a.dst2; base = a.eb2; no = a.no2; }
  if (gid >= a.eb3) { sp = a.src3; dp = a.dst3; base = a.eb3; no = a.no3; }
  if (gid >= a.eb4) { sp = a.src4; dp = a.dst4; base = a.eb4; no = a.no4; }
}

// ---- pass A: per-block bucket histogram ----
__global__ void bucket_count(BuildArgs a, int* __restrict__ counts, int NB, int chunk) {
  __shared__ int h[MAXNB];
  for (int i = threadIdx.x; i < NB; i += 256) h[i] = 0;
  __syncthreads();
  int b = blockIdx.x;
  int lo = b * chunk;
  int hi = lo + chunk; if (hi > a.eb5) hi = a.eb5;
  for (int e = lo + threadIdx.x; e < hi; e += 256) {
    const int *sp, *dp; int base, no;
    resolve(a, e, sp, dp, base, no);
    int g = no + dp[e - base];
    atomicAdd(&h[g >> BSH], 1);
  }
  __syncthreads();
  for (int i = threadIdx.x; i < NB; i += 256) counts[b * NB + i] = h[i];
}

// ---- pass S1: per-bucket exclusive scan over the 512 block counts ----
__global__ void bucket_scan1(const int* __restrict__ counts, int* __restrict__ offs,
                             int* __restrict__ totals, int NB) {
  __shared__ int wsum[4];
  int j = blockIdx.x;
  int t = threadIdx.x;
  int v0 = counts[(2 * t) * NB + j];
  int v1 = counts[(2 * t + 1) * NB + j];
  int s = v0 + v1;
  int lane = t & 63, w = t >> 6;
  int v = s;
  #pragma unroll
  for (int o = 1; o < 64; o <<= 1) {
    int u = __shfl_up(v, o);
    if (lane >= o) v += u;
  }
  if (lane == 63) wsum[w] = v;
  __syncthreads();
  int off = v - s;
  for (int i = 0; i < w; ++i) off += wsum[i];
  offs[(2 * t) * NB + j] = off;
  offs[(2 * t + 1) * NB + j] = off + v0;
  if (t == 255) totals[j] = off + s;
}

// ---- pass S2: exclusive scan over bucket totals -> bases (in place) ----
__global__ void bucket_scan2(int* __restrict__ totals, int NB) {
  __shared__ int buf[MAXNB];
  __shared__ int wsum[4];
  int t = threadIdx.x;
  for (int i = t; i < MAXNB; i += 256) buf[i] = (i < NB) ? totals[i] : 0;
  __syncthreads();
  int e0 = buf[4 * t], e1 = buf[4 * t + 1], e2 = buf[4 * t + 2], e3 = buf[4 * t + 3];
  int s = e0 + e1 + e2 + e3;
  int lane = t & 63, w = t >> 6;
  int v = s;
  #pragma unroll
  for (int o = 1; o < 64; o <<= 1) {
    int u = __shfl_up(v, o);
    if (lane >= o) v += u;
  }
  if (lane == 63) wsum[w] = v;
  __syncthreads();
  int off = v - s;
  for (int i = 0; i < w; ++i) off += wsum[i];
  if (4 * t     < NB) totals[4 * t]     = off;
  if (4 * t + 1 < NB) totals[4 * t + 1] = off + e0;
  if (4 * t + 2 < NB) totals[4 * t + 2] = off + e0 + e1;
  if (4 * t + 3 < NB) totals[4 * t + 3] = off + e0 + e1 + e2;
}

// ---- pass B: partition edges into bucket-grouped (dst,src) arrays ----
__global__ void bucket_part(BuildArgs a, const int* __restrict__ offs,
                            const int* __restrict__ bases,
                            int* __restrict__ ebuf_d, int* __restrict__ ebuf_s,
                            int NB, int chunk) {
  __shared__ int cur[MAXNB];
  int b = blockIdx.x;
  for (int i = threadIdx.x; i < NB; i += 256) cur[i] = bases[i] + offs[b * NB + i];
  __syncthreads();
  int lo = b * chunk;
  int hi = lo + chunk; if (hi > a.eb5) hi = a.eb5;
  for (int e = lo + threadIdx.x; e < hi; e += 256) {
    const int *sp, *dp; int base, no;
    resolve(a, e, sp, dp, base, no);
    int g = no + dp[e - base];
    int p = atomicAdd(&cur[g >> BSH], 1);
    ebuf_d[p] = g;
    ebuf_s[p] = sp[e - base];
  }
}

// ---- hist / scatter on bucketed edges (L2-local addresses) ----
__global__ void hist2_kernel(const int* __restrict__ ebuf_d, int* __restrict__ deg, int E) {
  int e = blockIdx.x * 256 + threadIdx.x;
  if (e < E) atomicAdd(&deg[ebuf_d[e]], 1);
}

__global__ void scatter2_kernel(const int* __restrict__ ebuf_d, const int* __restrict__ ebuf_s,
                                int* __restrict__ cursor, int* __restrict__ col, int E) {
  int e = blockIdx.x * 256 + threadIdx.x;
  if (e < E) {
    int p = atomicAdd(&cursor[ebuf_d[e]], 1);
    col[p] = ebuf_s[e];
  }
}

// ---- rowptr scans (unchanged) ----
__global__ void scan_block_sum(const int* __restrict__ deg, int* __restrict__ partials, int n) {
  __shared__ int red[256];
  int t = threadIdx.x;
  int base = blockIdx.x * 4096;
  int s = 0;
  #pragma unroll
  for (int i = 0; i < 16; ++i) {
    int idx = base + t + i * 256;
    if (idx < n) s += deg[idx];
  }
  red[t] = s;
  __syncthreads();
  for (int o = 128; o > 0; o >>= 1) {
    if (t < o) red[t] += red[t + o];
    __syncthreads();
  }
  if (t == 0) partials[blockIdx.x] = red[0];
}

__global__ void scan_partials_kernel(int* __restrict__ partials, int* __restrict__ rowptr,
                                     int nb, int n) {
  int run = 0;
  for (int i = 0; i < nb; ++i) { int v = partials[i]; partials[i] = run; run += v; }
  rowptr[n] = run;
}

__global__ void scan_within(int* __restrict__ deg_cursor, const int* __restrict__ partials,
                            int* __restrict__ rowptr, int n) {
  __shared__ int buf[4096];
  __shared__ int wsum[4];
  int t = threadIdx.x;
  int base = blockIdx.x * 4096;
  #pragma unroll
  for (int i = 0; i < 16; ++i) {
    int idx = base + t + i * 256;
    buf[t + i * 256] = (idx < n) ? deg_cursor[idx] : 0;
  }
  __syncthreads();
  int ex[16];
  int s = 0;
  #pragma unroll
  for (int i = 0; i < 16; ++i) { ex[i] = s; s += buf[t * 16 + i]; }
  int lane = t & 63, w = t >> 6;
  int v = s;
  #pragma unroll
  for (int o = 1; o < 64; o <<= 1) {
    int u = __shfl_up(v, o);
    if (lane >= o) v += u;
  }
  if (lane == 63) wsum[w] = v;
  __syncthreads();
  int off = partials[blockIdx.x] + (v - s);
  for (int i = 0; i < w; ++i) off += wsum[i];
  #pragma unroll
  for (int i = 0; i < 16; ++i) {
    int idx = base + t * 16 + i;
    if (idx < n) { int val = off + ex[i]; rowptr[idx] = val; deg_cursor[idx] = val; }
  }
}

// ---------------- fp32 -> f16 input conversion ----------------

__global__ void cvt_f2h_kernel(const float* __restrict__ in, half_t* __restrict__ out, int n8) {
  int i = blockIdx.x * 256 + threadIdx.x;
  if (i >= n8) return;
  const float4* p = (const float4*)(in + (size_t)i * 8);
  float4 a = p[0], b = p[1];
  f16x8 h = { (_Float16)a.x, (_Float16)a.y, (_Float16)a.z, (_Float16)a.w,
              (_Float16)b.x, (_Float16)b.y, (_Float16)b.z, (_Float16)b.w };
  *(f16x8*)(out + (size_t)i * 8) = h;
}

// ---------------- weight pack: fp32 row-major -> f16 MFMA B-fragment order ----

__global__ void pack_all_kernel(const float* __restrict__ Wl_t, const float* __restrict__ Wr_t,
                                const float* __restrict__ Wl_s, const float* __restrict__ Wr_s,
                                half_t* __restrict__ out) {
  int gid = blockIdx.x * 256 + threadIdx.x;
  if (gid >= 20 * 2048) return;
  int lane = gid & 63;
  int nt   = (gid >> 6) & 7;
  int kt   = (gid >> 9) & 3;
  int mat  = gid >> 11;
  const float* w;
  if (mat < 6)       w = Wl_t + (size_t)mat * MSZ;
  else if (mat < 12) w = Wr_t + (size_t)(mat - 6) * MSZ;
  else if (mat < 16) w = Wl_s + (size_t)(mat - 12) * MSZ;
  else               w = Wr_s + (size_t)(mat - 16) * MSZ;
  half_t* o = out + (size_t)mat * MSZ + (size_t)(((kt * 8 + nt) * 64 + lane)) * 8;
  int kbase = kt * 32 + (lane >> 4) * 8;
  int n = nt * 16 + (lane & 15);
  #pragma unroll
  for (int i = 0; i < 8; ++i) o[i] = (_Float16)w[(size_t)(kbase + i) * HDIM + n];
}

// ---------------- gather: mean-aggregate, f16 rows, 2-wide edge batching ----

__device__ __forceinline__ void gather_mean_h(const half_t* __restrict__ xsrc,
                                              const int* __restrict__ rowptr,
                                              const int* __restrict__ colidx,
                                              int node, int f0, float (&a)[16]) {
  #pragma unroll
  for (int j = 0; j < 16; ++j) a[j] = 0.f;
  int beg = rowptr[node];
  int end = rowptr[node + 1];
  for (int e = beg; e < end; e += 2) {
    int e1 = (e + 1 < end) ? e + 1 : e;
    float w1 = (e + 1 < end) ? 1.f : 0.f;
    int c0 = colidx[e], c1 = colidx[e1];
    const half_t* r0 = &xsrc[(size_t)c0 * HDIM + f0];
    const half_t* r1 = &xsrc[(size_t)c1 * HDIM + f0];
    f16x8 p0 = *(const f16x8*)r0;
    f16x8 p1 = *(const f16x8*)(r0 + 8);
    f16x8 q0 = *(const f16x8*)r1;
    f16x8 q1 = *(const f16x8*)(r1 + 8);
    #pragma unroll
    for (int j = 0; j < 8; ++j) {
      a[j]     += (float)p0[j] + w1 * (float)q0[j];
      a[j + 8] += (float)p1[j] + w1 * (float)q1[j];
    }
  }
  int dg = end - beg;
  if (dg > 0) {
    float inv = 1.0f / (float)dg;
    #pragma unroll
    for (int j = 0; j < 16; ++j) a[j] *= inv;
  }
}

// swizzled LDS tile store: [node][feat] f16, byte ^= (ni&7)<<4
__device__ __forceinline__ void st_tile_h(half_t* __restrict__ tile, int ni, int c,
                                          f16x8 lo, f16x8 hi) {
  unsigned sw = (unsigned)(ni & 7) << 4;
  unsigned b0 = (unsigned)(ni * 256 + c * 32);
  *(f16x8*)((char*)tile + ((b0     ) ^ sw)) = lo;
  *(f16x8*)((char*)tile + ((b0 + 16) ^ sw)) = hi;
}

__device__ __forceinline__ void st_tile_f(half_t* __restrict__ tile, int ni, int c,
                                          const float (&a)[16]) {
  f16x8 lo, hi;
  #pragma unroll
  for (int j = 0; j < 8; ++j) { lo[j] = (_Float16)a[j]; hi[j] = (_Float16)a[j + 8]; }
  st_tile_h(tile, ni, c, lo, hi);
}

// ---------------- simple SAGE block: out = lrelu(normalize(agg@Wl+bl+x@Wr)) ----

__device__ __forceinline__ void sage_simple_block(
    int n0, int n_dst,
    const half_t* __restrict__ xsrc, const half_t* __restrict__ xdst,
    const int* __restrict__ rowptr, const int* __restrict__ colidx,
    const half_t* __restrict__ pWl, const float* __restrict__ bl,
    const half_t* __restrict__ pWr,
    half_t* __restrict__ out_h, float* __restrict__ out_f, int wf32,
    half_t* __restrict__ lds_a, half_t* __restrict__ lds_x, float (*lds_nrm)[4],
    int tid)
{
  // phase 1
  {
    int ni = tid >> 3, c = tid & 7, f0 = c * 16;
    int node = n0 + ni;
    f16x8 x0 = f16x8_zero(), x1 = f16x8_zero();
    float a[16];
    #pragma unroll
    for (int j = 0; j < 16; ++j) a[j] = 0.f;
    if (node < n_dst) {
      const half_t* xd = &xdst[(size_t)node * HDIM + f0];
      x0 = *(const f16x8*)xd;
      x1 = *(const f16x8*)(xd + 8);
      gather_mean_h(xsrc, rowptr, colidx, node, f0, a);
    }
    st_tile_h(lds_x, ni, c, x0, x1);
    st_tile_f(lds_a, ni, c, a);
  }
  __syncthreads();

  // phase 2
  int lane = tid & 63, wid = tid >> 6;
  int m0 = (wid & 1) * 16;
  int colbase = (wid >> 1) * 64;
  int lg = lane >> 4, ln = lane & 15;

  f16x8 aag[4], axx[4];
  {
    int row = m0 + ln;
    unsigned rsw = (unsigned)(row & 7) << 4;
    #pragma unroll
    for (int kt = 0; kt < 4; ++kt) {
      unsigned byt = ((unsigned)(row * 256 + kt * 64 + lg * 16)) ^ rsw;
      aag[kt] = *(const f16x8*)((const char*)lds_a + byt);
      axx[kt] = *(const f16x8*)((const char*)lds_x + byt);
    }
  }

  f32x4 acc[4];
  #pragma unroll
  for (int t = 0; t < 4; ++t) {
    float blv = bl[colbase + t * 16 + ln];
    acc[t] = (f32x4){blv, blv, blv, blv};
  }

  #pragma unroll
  for (int t = 0; t < 4; ++t) {
    int ntg = (colbase >> 4) + t;
    #pragma unroll
    for (int kt = 0; kt < 4; ++kt) {
      size_t boff = (size_t)(((kt * 8 + ntg) * 64 + lane)) * 8;
      f16x8 bwl = *(const f16x8*)(pWl + boff);
      f16x8 bwr = *(const f16x8*)(pWr + boff);
      acc[t] = __builtin_amdgcn_mfma_f32_16x16x32_f16(aag[kt], bwl, acc[t], 0, 0, 0);
      acc[t] = __builtin_amdgcn_mfma_f32_16x16x32_f16(axx[kt], bwr, acc[t], 0, 0, 0);
    }
  }

  // phase 3
  float ss[4];
  #pragma unroll
  for (int r = 0; r < 4; ++r) {
    ss[r] = acc[0][r]*acc[0][r] + acc[1][r]*acc[1][r] + acc[2][r]*acc[2][r] + acc[3][r]*acc[3][r];
    ss[r] += __shfl_xor(ss[r], 1);
    ss[r] += __shfl_xor(ss[r], 2);
    ss[r] += __shfl_xor(ss[r], 4);
    ss[r] += __shfl_xor(ss[r], 8);
  }
  if (ln == 0) {
    #pragma unroll
    for (int r = 0; r < 4; ++r) lds_nrm[m0 + lg * 4 + r][wid >> 1] = ss[r];
  }
  __syncthreads();

  #pragma unroll
  for (int r = 0; r < 4; ++r) {
    int m = m0 + lg * 4 + r;
    int node = n0 + m;
    float tot = lds_nrm[m][0] + lds_nrm[m][1];
    float inv = 1.0f / fmaxf(sqrtf(tot), 1e-12f);
    if (node < n_dst) {
      #pragma unroll
      for (int t = 0; t < 4; ++t) {
        int col = colbase + t * 16 + ln;
        float v = acc[t][r] * inv;
        v = (v >= 0.f) ? v : 0.01f * v;
        if (wf32) out_f[(size_t)node * HDIM + col] = v;
        else      out_h[(size_t)node * HDIM + col] = (_Float16)v;
      }
    }
  }
}

// ---------------- temporal combo: fused con (csrc+cdst) + ipip ----------------

__global__ __launch_bounds__(256, 6) void temporal_kernel(
    const half_t* __restrict__ x_ip, const half_t* __restrict__ x_con,
    const int* __restrict__ rp_ipip, const int* __restrict__ rp_csrc, const int* __restrict__ rp_cdst,
    const int* __restrict__ col_all,
    const half_t* __restrict__ pWl_ip, const float* __restrict__ bl_ip, const half_t* __restrict__ pWr_ip,
    const half_t* __restrict__ pWl_c1, const float* __restrict__ bl_c1, const half_t* __restrict__ pWr_c1,
    const half_t* __restrict__ pWl_c2, const float* __restrict__ bl_c2, const half_t* __restrict__ pWr_c2,
    half_t* __restrict__ Y_ip, half_t* __restrict__ Y_con,
    int n_ip, int n_con, int nb_con)
{
  __shared__ half_t lds[3 * NT * HDIM] __attribute__((aligned(16)));
  __shared__ float lds_nrm[NT][4];
  int tid = threadIdx.x;

  if ((int)blockIdx.x >= nb_con) {
    int n0 = ((int)blockIdx.x - nb_con) * NT;
    sage_simple_block(n0, n_ip, x_ip, x_ip, rp_ipip, col_all,
                      pWl_ip, bl_ip, pWr_ip, Y_ip, nullptr, 0,
                      lds, lds + NT * HDIM, lds_nrm, tid);
    return;
  }

  int n0 = (int)blockIdx.x * NT;
  half_t* lds_x  = lds;
  half_t* lds_a1 = lds + NT * HDIM;
  half_t* lds_a2 = lds + 2 * NT * HDIM;

  {
    int ni = tid >> 3, c = tid & 7, f0 = c * 16;
    int node = n0 + ni;
    f16x8 x0 = f16x8_zero(), x1 = f16x8_zero();
    float a[16];
    #pragma unroll
    for (int j = 0; j < 16; ++j) a[j] = 0.f;
    if (node < n_con) {
      const half_t* xd = &x_con[(size_t)node * HDIM + f0];
      x0 = *(const f16x8*)xd;
      x1 = *(const f16x8*)(xd + 8);
    }
    st_tile_h(lds_x, ni, c, x0, x1);
    if (node < n_con) {
      gather_mean_h(x_con, rp_csrc, col_all, node, f0, a);
    }
    st_tile_f(lds_a1, ni, c, a);
    if (node < n_con) {
      gather_mean_h(x_con, rp_cdst, col_all, node, f0, a);
    } else {
      #pragma unroll
      for (int j = 0; j < 16; ++j) a[j] = 0.f;
    }
    st_tile_f(lds_a2, ni, c, a);
  }
  __syncthreads();

  int lane = tid & 63, wid = tid >> 6;
  int m0 = (wid & 1) * 16;
  int colbase = (wid >> 1) * 64;
  int lg = lane >> 4, ln = lane & 15;
  int row = m0 + ln;
  unsigned rsw = (unsigned)(row & 7) << 4;
  unsigned byt[4];
  #pragma unroll
  for (int kt = 0; kt < 4; ++kt)
    byt[kt] = ((unsigned)(row * 256 + kt * 64 + lg * 16)) ^ rsw;

  f16x8 axx[4], afr[4];
  #pragma unroll
  for (int kt = 0; kt < 4; ++kt) axx[kt] = *(const f16x8*)((const char*)lds_x + byt[kt]);

  f32x4 acc1[4], acc2[4];
  #pragma unroll
  for (int t = 0; t < 4; ++t) {
    float b1 = bl_c1[colbase + t * 16 + ln];
    float b2 = bl_c2[colbase + t * 16 + ln];
    acc1[t] = (f32x4){b1, b1, b1, b1};
    acc2[t] = (f32x4){b2, b2, b2, b2};
  }

  #pragma unroll
  for (int kt = 0; kt < 4; ++kt) afr[kt] = *(const f16x8*)((const char*)lds_a1 + byt[kt]);
  #pragma unroll
  for (int t = 0; t < 4; ++t) {
    int ntg = (colbase >> 4) + t;
    #pragma unroll
    for (int kt = 0; kt < 4; ++kt) {
      size_t boff = (size_t)(((kt * 8 + ntg) * 64 + lane)) * 8;
      f16x8 bwl = *(const f16x8*)(pWl_c1 + boff);
      f16x8 bwr = *(const f16x8*)(pWr_c1 + boff);
      acc1[t] = __builtin_amdgcn_mfma_f32_16x16x32_f16(afr[kt], bwl, acc1[t], 0, 0, 0);
      acc1[t] = __builtin_amdgcn_mfma_f32_16x16x32_f16(axx[kt], bwr, acc1[t], 0, 0, 0);
    }
  }
  #pragma unroll
  for (int kt = 0; kt < 4; ++kt) afr[kt] = *(const f16x8*)((const char*)lds_a2 + byt[kt]);
  #pragma unroll
  for (int t = 0; t < 4; ++t) {
    int ntg = (colbase >> 4) + t;
    #pragma unroll
    for (int kt = 0; kt < 4; ++kt) {
      size_t boff = (size_t)(((kt * 8 + ntg) * 64 + lane)) * 8;
      f16x8 bwl = *(const f16x8*)(pWl_c2 + boff);
      f16x8 bwr = *(const f16x8*)(pWr_c2 + boff);
      acc2[t] = __builtin_amdgcn_mfma_f32_16x16x32_f16(afr[kt], bwl, acc2[t], 0, 0, 0);
      acc2[t] = __builtin_amdgcn_mfma_f32_16x16x32_f16(axx[kt], bwr, acc2[t], 0, 0, 0);
    }
  }

  float ss1[4], ss2[4];
  #pragma unroll
  for (int r = 0; r < 4; ++r) {
    ss1[r] = acc1[0][r]*acc1[0][r] + acc1[1][r]*acc1[1][r] + acc1[2][r]*acc1[2][r] + acc1[3][r]*acc1[3][r];
    ss2[r] = acc2[0][r]*acc2[0][r] + acc2[1][r]*acc2[1][r] + acc2[2][r]*acc2[2][r] + acc2[3][r]*acc2[3][r];
    #pragma unroll
    for (int o = 1; o < 16; o <<= 1) {
      ss1[r] += __shfl_xor(ss1[r], o);
      ss2[r] += __shfl_xor(ss2[r], o);
    }
  }
  if (ln == 0) {
    #pragma unroll
    for (int r = 0; r < 4; ++r) {
      lds_nrm[m0 + lg * 4 + r][(wid >> 1)]     = ss1[r];
      lds_nrm[m0 + lg * 4 + r][2 + (wid >> 1)] = ss2[r];
    }
  }
  __syncthreads();

  #pragma unroll
  for (int r = 0; r < 4; ++r) {
    int m = m0 + lg * 4 + r;
    int node = n0 + m;
    float inv1 = 1.0f / fmaxf(sqrtf(lds_nrm[m][0] + lds_nrm[m][1]), 1e-12f);
    float inv2 = 1.0f / fmaxf(sqrtf(lds_nrm[m][2] + lds_nrm[m][3]), 1e-12f);
    if (node < n_con) {
      #pragma unroll
      for (int t = 0; t < 4; ++t) {
        int col = colbase + t * 16 + ln;
        float v = acc1[t][r] * inv1 + acc2[t][r] * inv2;
        v = (v >= 0.f) ? v : 0.01f * v;
        Y_con[(size_t)node * HDIM + col] = (_Float16)v;
      }
    }
  }
}

// ---------------- spatial combo: ipcon + conip ----------------

__global__ __launch_bounds__(256, 8) void spatial_kernel(
    const half_t* __restrict__ Y_ip, const half_t* __restrict__ Y_con,
    const int* __restrict__ rp_ipcon, const int* __restrict__ rp_conip,
    const int* __restrict__ col_all,
    const half_t* __restrict__ pWl_ic, const float* __restrict__ bl_ic, const half_t* __restrict__ pWr_ic,
    const half_t* __restrict__ pWl_ci, const float* __restrict__ bl_ci, const half_t* __restrict__ pWr_ci,
    half_t* __restrict__ zh_ip, half_t* __restrict__ zh_con,
    float* __restrict__ out_ip, float* __restrict__ out_con,
    int wf32, int n_ip, int n_con, int nb_con)
{
  __shared__ half_t lds[2 * NT * HDIM] __attribute__((aligned(16)));
  __shared__ float lds_nrm[NT][4];
  int tid = threadIdx.x;

  if ((int)blockIdx.x < nb_con) {
    int n0 = (int)blockIdx.x * NT;
    sage_simple_block(n0, n_con, Y_ip, Y_con, rp_ipcon, col_all,
                      pWl_ic, bl_ic, pWr_ic, zh_con, out_con, wf32,
                      lds, lds + NT * HDIM, lds_nrm, tid);
  } else {
    int n0 = ((int)blockIdx.x - nb_con) * NT;
    sage_simple_block(n0, n_ip, Y_con, Y_ip, rp_conip, col_all,
                      pWl_ci, bl_ci, pWr_ci, zh_ip, out_ip, wf32,
                      lds, lds + NT * HDIM, lds_nrm, tid);
  }
}

// ---------------- host launch ----------------

extern "C" void kernel_launch(void* const* d_in, const int* in_sizes, int n_in,
                              void* d_out, int out_size, void* d_ws, size_t ws_size,
                              hipStream_t stream) {
  (void)n_in; (void)out_size; (void)ws_size;
  const float* x_ip  = (const float*)d_in[0];
  const float* x_con = (const float*)d_in[1];
  const int* src_ipcon = (const int*)d_in[2];
  const int* dst_ipcon = (const int*)d_in[3];
  const int* src_conip = (const int*)d_in[4];
  const int* dst_conip = (const int*)d_in[5];
  const int* src_ipip  = (const int*)d_in[6];
  const int* dst_ipip  = (const int*)d_in[7];
  const int* src_csrc  = (const int*)d_in[8];
  const int* dst_csrc  = (const int*)d_in[9];
  const int* src_cdst  = (const int*)d_in[10];
  const int* dst_cdst  = (const int*)d_in[11];
  const float* Wl_t = (const float*)d_in[12];
  const float* bl_t = (const float*)d_in[13];
  const float* Wr_t = (const float*)d_in[14];
  const float* Wl_s = (const float*)d_in[15];
  const float* bl_s = (const float*)d_in[16];
  const float* Wr_s = (const float*)d_in[17];

  const int n_ip  = in_sizes[0] / HDIM;
  const int n_con = in_sizes[1] / HDIM;
  const int E_ipcon = in_sizes[2];
  const int E_conip = in_sizes[4];
  const int E_ipip  = in_sizes[6];
  const int E_csrc  = in_sizes[8];
  const int E_cdst  = in_sizes[10];

  const int no_ipip  = 0;
  const int no_csrc  = n_ip;
  const int no_cdst  = n_ip + n_con;
  const int no_ipcon = n_ip + 2 * n_con;
  const int no_conip = n_ip + 3 * n_con;
  const int Ntot = 2 * n_ip + 3 * n_con;
  const int eb1 = E_ipip;
  const int eb2 = eb1 + E_csrc;
  const int eb3 = eb2 + E_cdst;
  const int eb4 = eb3 + E_ipcon;
  const int Etot = eb4 + E_conip;
  const int NB = (Ntot + (1 << BSH) - 1) >> BSH;   // <= MAXNB for this problem
  const int chunk = (Etot + NBLK - 1) / NBLK;

  char* ws = (char*)d_ws;
  size_t off = 0;
  auto alloc = [&](size_t bytes) -> void* {
    off = (off + 255) & ~(size_t)255;
    void* p = ws + off;
    off += bytes;
    return p;
  };
  half_t* xh_ip  = (half_t*)alloc((size_t)n_ip * HDIM * 2);
  half_t* xh_con = (half_t*)alloc((size_t)n_con * HDIM * 2);
  half_t* Yh_ip  = (half_t*)alloc((size_t)n_ip * HDIM * 2);
  half_t* Yh_con = (half_t*)alloc((size_t)n_con * HDIM * 2);
  int* cur_all = (int*)alloc((size_t)Ntot * 4);
  int* rp_all  = (int*)alloc((size_t)(Ntot + 1) * 4);
  int* col_all = (int*)alloc((size_t)Etot * 4);
  int* partials = (int*)alloc(256 * 4);
  int* counts  = (int*)alloc((size_t)NBLK * NB * 4);
  int* offs    = (int*)alloc((size_t)NBLK * NB * 4);
  int* totals  = (int*)alloc((size_t)MAXNB * 4);
  int* ebuf_d  = (int*)alloc((size_t)Etot * 4);
  int* ebuf_s  = (int*)alloc((size_t)Etot * 4);
  half_t* pW = (half_t*)alloc((size_t)20 * MSZ * 2);

  (void)hipMemsetAsync(cur_all, 0, (size_t)Ntot * 4, stream);

  BuildArgs ba;
  ba.src0 = src_ipip;  ba.dst0 = dst_ipip;
  ba.src1 = src_csrc;  ba.dst1 = dst_csrc;
  ba.src2 = src_cdst;  ba.dst2 = dst_cdst;
  ba.src3 = src_ipcon; ba.dst3 = dst_ipcon;
  ba.src4 = src_conip; ba.dst4 = dst_conip;
  ba.eb1 = eb1; ba.eb2 = eb2; ba.eb3 = eb3; ba.eb4 = eb4; ba.eb5 = Etot;
  ba.no0 = no_ipip; ba.no1 = no_csrc; ba.no2 = no_cdst; ba.no3 = no_ipcon; ba.no4 = no_conip;

  cvt_f2h_kernel<<<(n_ip * HDIM / 8 + 255) / 256, 256, 0, stream>>>(x_ip, xh_ip, n_ip * HDIM / 8);
  cvt_f2h_kernel<<<(n_con * HDIM / 8 + 255) / 256, 256, 0, stream>>>(x_con, xh_con, n_con * HDIM / 8);
  pack_all_kernel<<<(20 * 2048 + 255) / 256, 256, 0, stream>>>(Wl_t, Wr_t, Wl_s, Wr_s, pW);

  // bucketed CSR build
  bucket_count<<<NBLK, 256, 0, stream>>>(ba, counts, NB, chunk);
  bucket_scan1<<<NB, 256, 0, stream>>>(counts, offs, totals, NB);
  bucket_scan2<<<1, 256, 0, stream>>>(totals, NB);
  bucket_part<<<NBLK, 256, 0, stream>>>(ba, offs, totals, ebuf_d, ebuf_s, NB, chunk);
  hist2_kernel<<<(Etot + 255) / 256, 256, 0, stream>>>(ebuf_d, cur_all, Etot);
  int nb = (Ntot + 4095) / 4096;
  scan_block_sum<<<nb, 256, 0, stream>>>(cur_all, partials, Ntot);
  scan_partials_kernel<<<1, 1, 0, stream>>>(partials, rp_all, nb, Ntot);
  scan_within<<<nb, 256, 0, stream>>>(cur_all, partials, rp_all, Ntot);
  scatter2_kernel<<<(Etot + 255) / 256, 256, 0, stream>>>(ebuf_d, ebuf_s, cur_all, col_all, Etot);

  float* out_ip  = (float*)d_out;
  float* out_con = (float*)d_out + (size_t)n_ip * HDIM;

  const int nb_con = (n_con + NT - 1) / NT;
  const int nb_ip  = (n_ip + NT - 1) / NT;

  const half_t* cip  = xh_ip;
  const half_t* ccon = xh_con;
  for (int l = 0; l < 2; ++l) {
    const half_t* pWl_ip = pW + (size_t)(l * 3 + 0) * MSZ;
    const half_t* pWr_ip = pW + (size_t)(6 + l * 3 + 0) * MSZ;
    const half_t* pWl_c1 = pW + (size_t)(l * 3 + 1) * MSZ;
    const half_t* pWr_c1 = pW + (size_t)(6 + l * 3 + 1) * MSZ;
    const half_t* pWl_c2 = pW + (size_t)(l * 3 + 2) * MSZ;
    const half_t* pWr_c2 = pW + (size_t)(6 + l * 3 + 2) * MSZ;
    temporal_kernel<<<nb_con + nb_ip, 256, 0, stream>>>(
        cip, ccon,
        rp_all + no_ipip, rp_all + no_csrc, rp_all + no_cdst, col_all,
        pWl_ip, bl_t + (l * 3 + 0) * HDIM, pWr_ip,
        pWl_c1, bl_t + (l * 3 + 1) * HDIM, pWr_c1,
        pWl_c2, bl_t + (l * 3 + 2) * HDIM, pWr_c2,
        Yh_ip, Yh_con, n_ip, n_con, nb_con);

    const half_t* pWl_ic = pW + (size_t)(12 + l * 2 + 0) * MSZ;
    const half_t* pWr_ic = pW + (size_t)(16 + l * 2 + 0) * MSZ;
    const half_t* pWl_ci = pW + (size_t)(12 + l * 2 + 1) * MSZ;
    const half_t* pWr_ci = pW + (size_t)(16 + l * 2 + 1) * MSZ;
    spatial_kernel<<<nb_con + nb_ip, 256, 0, stream>>>(
        Yh_ip, Yh_con,
        rp_all + no_ipcon, rp_all + no_conip, col_all,
        pWl_ic, bl_s + (l * 2 + 0) * HDIM, pWr_ic,
        pWl_ci, bl_s + (l * 2 + 1) * HDIM, pWr_ci,
        xh_ip, xh_con, out_ip, out_con, (l == 1) ? 1 : 0,
        n_ip, n_con, nb_con);

    cip = xh_ip;
    ccon = xh_con;
  }
}

// Round 12
// 630.541 us; speedup vs baseline: 7.0617x; 1.0321x over previous
//
#include <hip/hip_runtime.h>

#define HDIM 128
#define NT 32
#define MSZ (HDIM * HDIM)
#define NBLK 512        // blocks for bucket passes
#define MAXNB 1024      // max buckets (Ntot < 1M nodes)
#define BSH 10          // bucket = global_node >> BSH

typedef _Float16 half_t;
typedef __attribute__((ext_vector_type(8))) _Float16 f16x8;
typedef __attribute__((ext_vector_type(4))) float f32x4;

__device__ __forceinline__ f16x8 f16x8_zero() {
  f16x8 v = {0, 0, 0, 0, 0, 0, 0, 0};
  return v;
}

// ---------------- combined edge domain ----------------
// Node domain: [ipip(n_ip) | csrc(n_con) | cdst(n_con) | ipcon(n_con) | conip(n_ip)]

struct BuildArgs {
  const int* src0; const int* dst0;
  const int* src1; const int* dst1;
  const int* src2; const int* dst2;
  const int* src3; const int* dst3;
  const int* src4; const int* dst4;
  int eb1, eb2, eb3, eb4, eb5;
  int no0, no1, no2, no3, no4;
};

__device__ __forceinline__ void resolve(const BuildArgs& a, int gid,
                                        const int*& sp, const int*& dp, int& base, int& no) {
  sp = a.src0; dp = a.dst0; base = 0; no = a.no0;
  if (gid >= a.eb1) { sp = a.src1; dp = a.dst1; base = a.eb1; no = a.no1; }
  if (gid >= a.eb2) { sp = a.src2; dp = a.dst2; base = a.eb2; no = a.no2; }
  if (gid >= a.eb3) { sp = a.src3; dp = a.dst3; base = a.eb3; no = a.no3; }
  if (gid >= a.eb4) { sp = a.src4; dp = a.dst4; base = a.eb4; no = a.no4; }
}

// ---- pass A: per-block bucket histogram ----
__global__ void bucket_count(BuildArgs a, int* __restrict__ counts, int NB, int chunk) {
  __shared__ int h[MAXNB];
  for (int i = threadIdx.x; i < NB; i += 256) h[i] = 0;
  __syncthreads();
  int b = blockIdx.x;
  int lo = b * chunk;
  int hi = lo + chunk; if (hi > a.eb5) hi = a.eb5;
  for (int e = lo + threadIdx.x; e < hi; e += 256) {
    const int *sp, *dp; int base, no;
    resolve(a, e, sp, dp, base, no);
    int g = no + dp[e - base];
    atomicAdd(&h[g >> BSH], 1);
  }
  __syncthreads();
  for (int i = threadIdx.x; i < NB; i += 256) counts[b * NB + i] = h[i];
}

// ---- pass S1: per-bucket exclusive scan over the 512 block counts ----
__global__ void bucket_scan1(const int* __restrict__ counts, int* __restrict__ offs,
                             int* __restrict__ totals, int NB) {
  __shared__ int wsum[4];
  int j = blockIdx.x;
  int t = threadIdx.x;
  int v0 = counts[(2 * t) * NB + j];
  int v1 = counts[(2 * t + 1) * NB + j];
  int s = v0 + v1;
  int lane = t & 63, w = t >> 6;
  int v = s;
  #pragma unroll
  for (int o = 1; o < 64; o <<= 1) {
    int u = __shfl_up(v, o);
    if (lane >= o) v += u;
  }
  if (lane == 63) wsum[w] = v;
  __syncthreads();
  int off = v - s;
  for (int i = 0; i < w; ++i) off += wsum[i];
  offs[(2 * t) * NB + j] = off;
  offs[(2 * t + 1) * NB + j] = off + v0;
  if (t == 255) totals[j] = off + s;
}

// ---- pass S2: exclusive scan over bucket totals -> bases (in place) ----
__global__ void bucket_scan2(int* __restrict__ totals, int NB) {
  __shared__ int buf[MAXNB];
  __shared__ int wsum[4];
  int t = threadIdx.x;
  for (int i = t; i < MAXNB; i += 256) buf[i] = (i < NB) ? totals[i] : 0;
  __syncthreads();
  int e0 = buf[4 * t], e1 = buf[4 * t + 1], e2 = buf[4 * t + 2], e3 = buf[4 * t + 3];
  int s = e0 + e1 + e2 + e3;
  int lane = t & 63, w = t >> 6;
  int v = s;
  #pragma unroll
  for (int o = 1; o < 64; o <<= 1) {
    int u = __shfl_up(v, o);
    if (lane >= o) v += u;
  }
  if (lane == 63) wsum[w] = v;
  __syncthreads();
  int off = v - s;
  for (int i = 0; i < w; ++i) off += wsum[i];
  if (4 * t     < NB) totals[4 * t]     = off;
  if (4 * t + 1 < NB) totals[4 * t + 1] = off + e0;
  if (4 * t + 2 < NB) totals[4 * t + 2] = off + e0 + e1;
  if (4 * t + 3 < NB) totals[4 * t + 3] = off + e0 + e1 + e2;
}

// ---- pass B: partition edges into bucket-grouped (dst,src) arrays ----
__global__ void bucket_part(BuildArgs a, const int* __restrict__ offs,
                            const int* __restrict__ bases,
                            int* __restrict__ ebuf_d, int* __restrict__ ebuf_s,
                            int NB, int chunk) {
  __shared__ int cur[MAXNB];
  int b = blockIdx.x;
  for (int i = threadIdx.x; i < NB; i += 256) cur[i] = bases[i] + offs[b * NB + i];
  __syncthreads();
  int lo = b * chunk;
  int hi = lo + chunk; if (hi > a.eb5) hi = a.eb5;
  for (int e = lo + threadIdx.x; e < hi; e += 256) {
    const int *sp, *dp; int base, no;
    resolve(a, e, sp, dp, base, no);
    int g = no + dp[e - base];
    int p = atomicAdd(&cur[g >> BSH], 1);
    ebuf_d[p] = g;
    ebuf_s[p] = sp[e - base];
  }
}

// ---- hist / scatter on bucketed edges (L2-local addresses) ----
__global__ void hist2_kernel(const int* __restrict__ ebuf_d, int* __restrict__ deg, int E) {
  int e = blockIdx.x * 256 + threadIdx.x;
  if (e < E) atomicAdd(&deg[ebuf_d[e]], 1);
}

__global__ void scatter2_kernel(const int* __restrict__ ebuf_d, const int* __restrict__ ebuf_s,
                                int* __restrict__ cursor, int* __restrict__ col, int E) {
  int e = blockIdx.x * 256 + threadIdx.x;
  if (e < E) {
    int p = atomicAdd(&cursor[ebuf_d[e]], 1);
    col[p] = ebuf_s[e];
  }
}

// ---- rowptr scans ----
__global__ void scan_block_sum(const int* __restrict__ deg, int* __restrict__ partials, int n) {
  __shared__ int red[256];
  int t = threadIdx.x;
  int base = blockIdx.x * 4096;
  int s = 0;
  #pragma unroll
  for (int i = 0; i < 16; ++i) {
    int idx = base + t + i * 256;
    if (idx < n) s += deg[idx];
  }
  red[t] = s;
  __syncthreads();
  for (int o = 128; o > 0; o >>= 1) {
    if (t < o) red[t] += red[t + o];
    __syncthreads();
  }
  if (t == 0) partials[blockIdx.x] = red[0];
}

// parallel exclusive scan over <=256 block partials (was a 1-thread serial loop)
__global__ void scan_partials_kernel(int* __restrict__ partials, int* __restrict__ rowptr,
                                     int nb, int n) {
  __shared__ int wsum[4];
  int t = threadIdx.x;
  int v0 = (t < nb) ? partials[t] : 0;
  int lane = t & 63, w = t >> 6;
  int v = v0;
  #pragma unroll
  for (int o = 1; o < 64; o <<= 1) {
    int u = __shfl_up(v, o);
    if (lane >= o) v += u;
  }
  if (lane == 63) wsum[w] = v;
  __syncthreads();
  int off = v - v0;
  for (int i = 0; i < w; ++i) off += wsum[i];
  if (t < nb) partials[t] = off;
  if (t == 255) rowptr[n] = off + v0;
}

__global__ void scan_within(int* __restrict__ deg_cursor, const int* __restrict__ partials,
                            int* __restrict__ rowptr, int n) {
  __shared__ int buf[4096];
  __shared__ int wsum[4];
  int t = threadIdx.x;
  int base = blockIdx.x * 4096;
  #pragma unroll
  for (int i = 0; i < 16; ++i) {
    int idx = base + t + i * 256;
    buf[t + i * 256] = (idx < n) ? deg_cursor[idx] : 0;
  }
  __syncthreads();
  int ex[16];
  int s = 0;
  #pragma unroll
  for (int i = 0; i < 16; ++i) { ex[i] = s; s += buf[t * 16 + i]; }
  int lane = t & 63, w = t >> 6;
  int v = s;
  #pragma unroll
  for (int o = 1; o < 64; o <<= 1) {
    int u = __shfl_up(v, o);
    if (lane >= o) v += u;
  }
  if (lane == 63) wsum[w] = v;
  __syncthreads();
  int off = partials[blockIdx.x] + (v - s);
  for (int i = 0; i < w; ++i) off += wsum[i];
  #pragma unroll
  for (int i = 0; i < 16; ++i) {
    int idx = base + t * 16 + i;
    if (idx < n) { int val = off + ex[i]; rowptr[idx] = val; deg_cursor[idx] = val; }
  }
}

// ---------------- fp32 -> f16 input conversion ----------------

__global__ void cvt_f2h_kernel(const float* __restrict__ in, half_t* __restrict__ out, int n8) {
  int i = blockIdx.x * 256 + threadIdx.x;
  if (i >= n8) return;
  const float4* p = (const float4*)(in + (size_t)i * 8);
  float4 a = p[0], b = p[1];
  f16x8 h = { (_Float16)a.x, (_Float16)a.y, (_Float16)a.z, (_Float16)a.w,
              (_Float16)b.x, (_Float16)b.y, (_Float16)b.z, (_Float16)b.w };
  *(f16x8*)(out + (size_t)i * 8) = h;
}

// ---------------- weight pack: fp32 row-major -> f16 MFMA B-fragment order ----

__global__ void pack_all_kernel(const float* __restrict__ Wl_t, const float* __restrict__ Wr_t,
                                const float* __restrict__ Wl_s, const float* __restrict__ Wr_s,
                                half_t* __restrict__ out) {
  int gid = blockIdx.x * 256 + threadIdx.x;
  if (gid >= 20 * 2048) return;
  int lane = gid & 63;
  int nt   = (gid >> 6) & 7;
  int kt   = (gid >> 9) & 3;
  int mat  = gid >> 11;
  const float* w;
  if (mat < 6)       w = Wl_t + (size_t)mat * MSZ;
  else if (mat < 12) w = Wr_t + (size_t)(mat - 6) * MSZ;
  else if (mat < 16) w = Wl_s + (size_t)(mat - 12) * MSZ;
  else               w = Wr_s + (size_t)(mat - 16) * MSZ;
  half_t* o = out + (size_t)mat * MSZ + (size_t)(((kt * 8 + nt) * 64 + lane)) * 8;
  int kbase = kt * 32 + (lane >> 4) * 8;
  int n = nt * 16 + (lane & 15);
  #pragma unroll
  for (int i = 0; i < 8; ++i) o[i] = (_Float16)w[(size_t)(kbase + i) * HDIM + n];
}

// ---------------- gather: packed-f16 mean-aggregate (v_pk_add_f16 path) ----

__device__ __forceinline__ void gather_mean_pk(const half_t* __restrict__ xsrc,
                                               const int* __restrict__ rowptr,
                                               const int* __restrict__ colidx,
                                               int node, int f0, f16x8& s0, f16x8& s1) {
  s0 = f16x8_zero();
  s1 = f16x8_zero();
  int beg = rowptr[node];
  int end = rowptr[node + 1];
  for (int e = beg; e < end; e += 2) {
    bool has2 = (e + 1 < end);
    int c0 = colidx[e];
    int c1 = colidx[has2 ? e + 1 : e];
    const half_t* r0 = &xsrc[(size_t)c0 * HDIM + f0];
    const half_t* r1 = &xsrc[(size_t)c1 * HDIM + f0];
    f16x8 p0 = *(const f16x8*)r0;
    f16x8 p1 = *(const f16x8*)(r0 + 8);
    f16x8 q0 = *(const f16x8*)r1;
    f16x8 q1 = *(const f16x8*)(r1 + 8);
    if (!has2) { q0 = f16x8_zero(); q1 = f16x8_zero(); }
    s0 = s0 + p0 + q0;
    s1 = s1 + p1 + q1;
  }
  int dg = end - beg;
  if (dg > 1) {
    _Float16 hinv = (_Float16)(1.0f / (float)dg);
    #pragma unroll
    for (int j = 0; j < 8; ++j) { s0[j] *= hinv; s1[j] *= hinv; }
  }
}

// swizzled LDS tile store: [node][feat] f16, byte ^= (ni&7)<<4
__device__ __forceinline__ void st_tile_h(half_t* __restrict__ tile, int ni, int c,
                                          f16x8 lo, f16x8 hi) {
  unsigned sw = (unsigned)(ni & 7) << 4;
  unsigned b0 = (unsigned)(ni * 256 + c * 32);
  *(f16x8*)((char*)tile + ((b0     ) ^ sw)) = lo;
  *(f16x8*)((char*)tile + ((b0 + 16) ^ sw)) = hi;
}

// ---------------- simple SAGE block: out = lrelu(normalize(agg@Wl+bl+x@Wr)) ----

__device__ __forceinline__ void sage_simple_block(
    int n0, int n_dst,
    const half_t* __restrict__ xsrc, const half_t* __restrict__ xdst,
    const int* __restrict__ rowptr, const int* __restrict__ colidx,
    const half_t* __restrict__ pWl, const float* __restrict__ bl,
    const half_t* __restrict__ pWr,
    half_t* __restrict__ out_h, float* __restrict__ out_f, int wf32,
    half_t* __restrict__ lds_a, half_t* __restrict__ lds_x, float (*lds_nrm)[4],
    int tid)
{
  // phase 1
  {
    int ni = tid >> 3, c = tid & 7, f0 = c * 16;
    int node = n0 + ni;
    f16x8 x0 = f16x8_zero(), x1 = f16x8_zero();
    f16x8 s0 = f16x8_zero(), s1 = f16x8_zero();
    if (node < n_dst) {
      const half_t* xd = &xdst[(size_t)node * HDIM + f0];
      x0 = *(const f16x8*)xd;
      x1 = *(const f16x8*)(xd + 8);
      gather_mean_pk(xsrc, rowptr, colidx, node, f0, s0, s1);
    }
    st_tile_h(lds_x, ni, c, x0, x1);
    st_tile_h(lds_a, ni, c, s0, s1);
  }
  __syncthreads();

  // phase 2
  int lane = tid & 63, wid = tid >> 6;
  int m0 = (wid & 1) * 16;
  int colbase = (wid >> 1) * 64;
  int lg = lane >> 4, ln = lane & 15;

  f16x8 aag[4], axx[4];
  {
    int row = m0 + ln;
    unsigned rsw = (unsigned)(row & 7) << 4;
    #pragma unroll
    for (int kt = 0; kt < 4; ++kt) {
      unsigned byt = ((unsigned)(row * 256 + kt * 64 + lg * 16)) ^ rsw;
      aag[kt] = *(const f16x8*)((const char*)lds_a + byt);
      axx[kt] = *(const f16x8*)((const char*)lds_x + byt);
    }
  }

  f32x4 acc[4];
  #pragma unroll
  for (int t = 0; t < 4; ++t) {
    float blv = bl[colbase + t * 16 + ln];
    acc[t] = (f32x4){blv, blv, blv, blv};
  }

  #pragma unroll
  for (int t = 0; t < 4; ++t) {
    int ntg = (colbase >> 4) + t;
    #pragma unroll
    for (int kt = 0; kt < 4; ++kt) {
      size_t boff = (size_t)(((kt * 8 + ntg) * 64 + lane)) * 8;
      f16x8 bwl = *(const f16x8*)(pWl + boff);
      f16x8 bwr = *(const f16x8*)(pWr + boff);
      acc[t] = __builtin_amdgcn_mfma_f32_16x16x32_f16(aag[kt], bwl, acc[t], 0, 0, 0);
      acc[t] = __builtin_amdgcn_mfma_f32_16x16x32_f16(axx[kt], bwr, acc[t], 0, 0, 0);
    }
  }

  // phase 3
  float ss[4];
  #pragma unroll
  for (int r = 0; r < 4; ++r) {
    ss[r] = acc[0][r]*acc[0][r] + acc[1][r]*acc[1][r] + acc[2][r]*acc[2][r] + acc[3][r]*acc[3][r];
    ss[r] += __shfl_xor(ss[r], 1);
    ss[r] += __shfl_xor(ss[r], 2);
    ss[r] += __shfl_xor(ss[r], 4);
    ss[r] += __shfl_xor(ss[r], 8);
  }
  if (ln == 0) {
    #pragma unroll
    for (int r = 0; r < 4; ++r) lds_nrm[m0 + lg * 4 + r][wid >> 1] = ss[r];
  }
  __syncthreads();

  #pragma unroll
  for (int r = 0; r < 4; ++r) {
    int m = m0 + lg * 4 + r;
    int node = n0 + m;
    float tot = lds_nrm[m][0] + lds_nrm[m][1];
    float inv = 1.0f / fmaxf(sqrtf(tot), 1e-12f);
    if (node < n_dst) {
      #pragma unroll
      for (int t = 0; t < 4; ++t) {
        int col = colbase + t * 16 + ln;
        float v = acc[t][r] * inv;
        v = (v >= 0.f) ? v : 0.01f * v;
        if (wf32) out_f[(size_t)node * HDIM + col] = v;
        else      out_h[(size_t)node * HDIM + col] = (_Float16)v;
      }
    }
  }
}

// ---------------- temporal combo: fused con (csrc+cdst) + ipip ----------------

__global__ __launch_bounds__(256, 6) void temporal_kernel(
    const half_t* __restrict__ x_ip, const half_t* __restrict__ x_con,
    const int* __restrict__ rp_ipip, const int* __restrict__ rp_csrc, const int* __restrict__ rp_cdst,
    const int* __restrict__ col_all,
    const half_t* __restrict__ pWl_ip, const float* __restrict__ bl_ip, const half_t* __restrict__ pWr_ip,
    const half_t* __restrict__ pWl_c1, const float* __restrict__ bl_c1, const half_t* __restrict__ pWr_c1,
    const half_t* __restrict__ pWl_c2, const float* __restrict__ bl_c2, const half_t* __restrict__ pWr_c2,
    half_t* __restrict__ Y_ip, half_t* __restrict__ Y_con,
    int n_ip, int n_con, int nb_con)
{
  __shared__ half_t lds[3 * NT * HDIM] __attribute__((aligned(16)));
  __shared__ float lds_nrm[NT][4];
  int tid = threadIdx.x;

  if ((int)blockIdx.x >= nb_con) {
    int n0 = ((int)blockIdx.x - nb_con) * NT;
    sage_simple_block(n0, n_ip, x_ip, x_ip, rp_ipip, col_all,
                      pWl_ip, bl_ip, pWr_ip, Y_ip, nullptr, 0,
                      lds, lds + NT * HDIM, lds_nrm, tid);
    return;
  }

  int n0 = (int)blockIdx.x * NT;
  half_t* lds_x  = lds;
  half_t* lds_a1 = lds + NT * HDIM;
  half_t* lds_a2 = lds + 2 * NT * HDIM;

  {
    int ni = tid >> 3, c = tid & 7, f0 = c * 16;
    int node = n0 + ni;
    f16x8 x0 = f16x8_zero(), x1 = f16x8_zero();
    f16x8 s0 = f16x8_zero(), s1 = f16x8_zero();
    if (node < n_con) {
      const half_t* xd = &x_con[(size_t)node * HDIM + f0];
      x0 = *(const f16x8*)xd;
      x1 = *(const f16x8*)(xd + 8);
    }
    st_tile_h(lds_x, ni, c, x0, x1);
    if (node < n_con) gather_mean_pk(x_con, rp_csrc, col_all, node, f0, s0, s1);
    st_tile_h(lds_a1, ni, c, s0, s1);
    s0 = f16x8_zero(); s1 = f16x8_zero();
    if (node < n_con) gather_mean_pk(x_con, rp_cdst, col_all, node, f0, s0, s1);
    st_tile_h(lds_a2, ni, c, s0, s1);
  }
  __syncthreads();

  int lane = tid & 63, wid = tid >> 6;
  int m0 = (wid & 1) * 16;
  int colbase = (wid >> 1) * 64;
  int lg = lane >> 4, ln = lane & 15;
  int row = m0 + ln;
  unsigned rsw = (unsigned)(row & 7) << 4;
  unsigned byt[4];
  #pragma unroll
  for (int kt = 0; kt < 4; ++kt)
    byt[kt] = ((unsigned)(row * 256 + kt * 64 + lg * 16)) ^ rsw;

  f16x8 axx[4], afr[4];
  #pragma unroll
  for (int kt = 0; kt < 4; ++kt) axx[kt] = *(const f16x8*)((const char*)lds_x + byt[kt]);

  f32x4 acc1[4], acc2[4];
  #pragma unroll
  for (int t = 0; t < 4; ++t) {
    float b1 = bl_c1[colbase + t * 16 + ln];
    float b2 = bl_c2[colbase + t * 16 + ln];
    acc1[t] = (f32x4){b1, b1, b1, b1};
    acc2[t] = (f32x4){b2, b2, b2, b2};
  }

  #pragma unroll
  for (int kt = 0; kt < 4; ++kt) afr[kt] = *(const f16x8*)((const char*)lds_a1 + byt[kt]);
  #pragma unroll
  for (int t = 0; t < 4; ++t) {
    int ntg = (colbase >> 4) + t;
    #pragma unroll
    for (int kt = 0; kt < 4; ++kt) {
      size_t boff = (size_t)(((kt * 8 + ntg) * 64 + lane)) * 8;
      f16x8 bwl = *(const f16x8*)(pWl_c1 + boff);
      f16x8 bwr = *(const f16x8*)(pWr_c1 + boff);
      acc1[t] = __builtin_amdgcn_mfma_f32_16x16x32_f16(afr[kt], bwl, acc1[t], 0, 0, 0);
      acc1[t] = __builtin_amdgcn_mfma_f32_16x16x32_f16(axx[kt], bwr, acc1[t], 0, 0, 0);
    }
  }
  #pragma unroll
  for (int kt = 0; kt < 4; ++kt) afr[kt] = *(const f16x8*)((const char*)lds_a2 + byt[kt]);
  #pragma unroll
  for (int t = 0; t < 4; ++t) {
    int ntg = (colbase >> 4) + t;
    #pragma unroll
    for (int kt = 0; kt < 4; ++kt) {
      size_t boff = (size_t)(((kt * 8 + ntg) * 64 + lane)) * 8;
      f16x8 bwl = *(const f16x8*)(pWl_c2 + boff);
      f16x8 bwr = *(const f16x8*)(pWr_c2 + boff);
      acc2[t] = __builtin_amdgcn_mfma_f32_16x16x32_f16(afr[kt], bwl, acc2[t], 0, 0, 0);
      acc2[t] = __builtin_amdgcn_mfma_f32_16x16x32_f16(axx[kt], bwr, acc2[t], 0, 0, 0);
    }
  }

  float ss1[4], ss2[4];
  #pragma unroll
  for (int r = 0; r < 4; ++r) {
    ss1[r] = acc1[0][r]*acc1[0][r] + acc1[1][r]*acc1[1][r] + acc1[2][r]*acc1[2][r] + acc1[3][r]*acc1[3][r];
    ss2[r] = acc2[0][r]*acc2[0][r] + acc2[1][r]*acc2[1][r] + acc2[2][r]*acc2[2][r] + acc2[3][r]*acc2[3][r];
    #pragma unroll
    for (int o = 1; o < 16; o <<= 1) {
      ss1[r] += __shfl_xor(ss1[r], o);
      ss2[r] += __shfl_xor(ss2[r], o);
    }
  }
  if (ln == 0) {
    #pragma unroll
    for (int r = 0; r < 4; ++r) {
      lds_nrm[m0 + lg * 4 + r][(wid >> 1)]     = ss1[r];
      lds_nrm[m0 + lg * 4 + r][2 + (wid >> 1)] = ss2[r];
    }
  }
  __syncthreads();

  #pragma unroll
  for (int r = 0; r < 4; ++r) {
    int m = m0 + lg * 4 + r;
    int node = n0 + m;
    float inv1 = 1.0f / fmaxf(sqrtf(lds_nrm[m][0] + lds_nrm[m][1]), 1e-12f);
    float inv2 = 1.0f / fmaxf(sqrtf(lds_nrm[m][2] + lds_nrm[m][3]), 1e-12f);
    if (node < n_con) {
      #pragma unroll
      for (int t = 0; t < 4; ++t) {
        int col = colbase + t * 16 + ln;
        float v = acc1[t][r] * inv1 + acc2[t][r] * inv2;
        v = (v >= 0.f) ? v : 0.01f * v;
        Y_con[(size_t)node * HDIM + col] = (_Float16)v;
      }
    }
  }
}

// ---------------- spatial combo: ipcon + conip ----------------

__global__ __launch_bounds__(256, 8) void spatial_kernel(
    const half_t* __restrict__ Y_ip, const half_t* __restrict__ Y_con,
    const int* __restrict__ rp_ipcon, const int* __restrict__ rp_conip,
    const int* __restrict__ col_all,
    const half_t* __restrict__ pWl_ic, const float* __restrict__ bl_ic, const half_t* __restrict__ pWr_ic,
    const half_t* __restrict__ pWl_ci, const float* __restrict__ bl_ci, const half_t* __restrict__ pWr_ci,
    half_t* __restrict__ zh_ip, half_t* __restrict__ zh_con,
    float* __restrict__ out_ip, float* __restrict__ out_con,
    int wf32, int n_ip, int n_con, int nb_con)
{
  __shared__ half_t lds[2 * NT * HDIM] __attribute__((aligned(16)));
  __shared__ float lds_nrm[NT][4];
  int tid = threadIdx.x;

  if ((int)blockIdx.x < nb_con) {
    int n0 = (int)blockIdx.x * NT;
    sage_simple_block(n0, n_con, Y_ip, Y_con, rp_ipcon, col_all,
                      pWl_ic, bl_ic, pWr_ic, zh_con, out_con, wf32,
                      lds, lds + NT * HDIM, lds_nrm, tid);
  } else {
    int n0 = ((int)blockIdx.x - nb_con) * NT;
    sage_simple_block(n0, n_ip, Y_con, Y_ip, rp_conip, col_all,
                      pWl_ci, bl_ci, pWr_ci, zh_ip, out_ip, wf32,
                      lds, lds + NT * HDIM, lds_nrm, tid);
  }
}

// ---------------- host launch ----------------

extern "C" void kernel_launch(void* const* d_in, const int* in_sizes, int n_in,
                              void* d_out, int out_size, void* d_ws, size_t ws_size,
                              hipStream_t stream) {
  (void)n_in; (void)out_size; (void)ws_size;
  const float* x_ip  = (const float*)d_in[0];
  const float* x_con = (const float*)d_in[1];
  const int* src_ipcon = (const int*)d_in[2];
  const int* dst_ipcon = (const int*)d_in[3];
  const int* src_conip = (const int*)d_in[4];
  const int* dst_conip = (const int*)d_in[5];
  const int* src_ipip  = (const int*)d_in[6];
  const int* dst_ipip  = (const int*)d_in[7];
  const int* src_csrc  = (const int*)d_in[8];
  const int* dst_csrc  = (const int*)d_in[9];
  const int* src_cdst  = (const int*)d_in[10];
  const int* dst_cdst  = (const int*)d_in[11];
  const float* Wl_t = (const float*)d_in[12];
  const float* bl_t = (const float*)d_in[13];
  const float* Wr_t = (const float*)d_in[14];
  const float* Wl_s = (const float*)d_in[15];
  const float* bl_s = (const float*)d_in[16];
  const float* Wr_s = (const float*)d_in[17];

  const int n_ip  = in_sizes[0] / HDIM;
  const int n_con = in_sizes[1] / HDIM;
  const int E_ipcon = in_sizes[2];
  const int E_conip = in_sizes[4];
  const int E_ipip  = in_sizes[6];
  const int E_csrc  = in_sizes[8];
  const int E_cdst  = in_sizes[10];

  const int no_ipip  = 0;
  const int no_csrc  = n_ip;
  const int no_cdst  = n_ip + n_con;
  const int no_ipcon = n_ip + 2 * n_con;
  const int no_conip = n_ip + 3 * n_con;
  const int Ntot = 2 * n_ip + 3 * n_con;
  const int eb1 = E_ipip;
  const int eb2 = eb1 + E_csrc;
  const int eb3 = eb2 + E_cdst;
  const int eb4 = eb3 + E_ipcon;
  const int Etot = eb4 + E_conip;
  const int NB = (Ntot + (1 << BSH) - 1) >> BSH;
  const int chunk = (Etot + NBLK - 1) / NBLK;

  char* ws = (char*)d_ws;
  size_t off = 0;
  auto alloc = [&](size_t bytes) -> void* {
    off = (off + 255) & ~(size_t)255;
    void* p = ws + off;
    off += bytes;
    return p;
  };
  half_t* xh_ip  = (half_t*)alloc((size_t)n_ip * HDIM * 2);
  half_t* xh_con = (half_t*)alloc((size_t)n_con * HDIM * 2);
  half_t* Yh_ip  = (half_t*)alloc((size_t)n_ip * HDIM * 2);
  half_t* Yh_con = (half_t*)alloc((size_t)n_con * HDIM * 2);
  int* cur_all = (int*)alloc((size_t)Ntot * 4);
  int* rp_all  = (int*)alloc((size_t)(Ntot + 1) * 4);
  int* col_all = (int*)alloc((size_t)Etot * 4);
  int* partials = (int*)alloc(256 * 4);
  int* counts  = (int*)alloc((size_t)NBLK * NB * 4);
  int* offs    = (int*)alloc((size_t)NBLK * NB * 4);
  int* totals  = (int*)alloc((size_t)MAXNB * 4);
  int* ebuf_d  = (int*)alloc((size_t)Etot * 4);
  int* ebuf_s  = (int*)alloc((size_t)Etot * 4);
  half_t* pW = (half_t*)alloc((size_t)20 * MSZ * 2);

  (void)hipMemsetAsync(cur_all, 0, (size_t)Ntot * 4, stream);

  BuildArgs ba;
  ba.src0 = src_ipip;  ba.dst0 = dst_ipip;
  ba.src1 = src_csrc;  ba.dst1 = dst_csrc;
  ba.src2 = src_cdst;  ba.dst2 = dst_cdst;
  ba.src3 = src_ipcon; ba.dst3 = dst_ipcon;
  ba.src4 = src_conip; ba.dst4 = dst_conip;
  ba.eb1 = eb1; ba.eb2 = eb2; ba.eb3 = eb3; ba.eb4 = eb4; ba.eb5 = Etot;
  ba.no0 = no_ipip; ba.no1 = no_csrc; ba.no2 = no_cdst; ba.no3 = no_ipcon; ba.no4 = no_conip;

  cvt_f2h_kernel<<<(n_ip * HDIM / 8 + 255) / 256, 256, 0, stream>>>(x_ip, xh_ip, n_ip * HDIM / 8);
  cvt_f2h_kernel<<<(n_con * HDIM / 8 + 255) / 256, 256, 0, stream>>>(x_con, xh_con, n_con * HDIM / 8);
  pack_all_kernel<<<(20 * 2048 + 255) / 256, 256, 0, stream>>>(Wl_t, Wr_t, Wl_s, Wr_s, pW);

  // bucketed CSR build
  bucket_count<<<NBLK, 256, 0, stream>>>(ba, counts, NB, chunk);
  bucket_scan1<<<NB, 256, 0, stream>>>(counts, offs, totals, NB);
  bucket_scan2<<<1, 256, 0, stream>>>(totals, NB);
  bucket_part<<<NBLK, 256, 0, stream>>>(ba, offs, totals, ebuf_d, ebuf_s, NB, chunk);
  hist2_kernel<<<(Etot + 255) / 256, 256, 0, stream>>>(ebuf_d, cur_all, Etot);
  int nb = (Ntot + 4095) / 4096;
  scan_block_sum<<<nb, 256, 0, stream>>>(cur_all, partials, Ntot);
  scan_partials_kernel<<<1, 256, 0, stream>>>(partials, rp_all, nb, Ntot);
  scan_within<<<nb, 256, 0, stream>>>(cur_all, partials, rp_all, Ntot);
  scatter2_kernel<<<(Etot + 255) / 256, 256, 0, stream>>>(ebuf_d, ebuf_s, cur_all, col_all, Etot);

  float* out_ip  = (float*)d_out;
  float* out_con = (float*)d_out + (size_t)n_ip * HDIM;

  const int nb_con = (n_con + NT - 1) / NT;
  const int nb_ip  = (n_ip + NT - 1) / NT;

  const half_t* cip  = xh_ip;
  const half_t* ccon = xh_con;
  for (int l = 0; l < 2; ++l) {
    const half_t* pWl_ip = pW + (size_t)(l * 3 + 0) * MSZ;
    const half_t* pWr_ip = pW + (size_t)(6 + l * 3 + 0) * MSZ;
    const half_t* pWl_c1 = pW + (size_t)(l * 3 + 1) * MSZ;
    const half_t* pWr_c1 = pW + (size_t)(6 + l * 3 + 1) * MSZ;
    const half_t* pWl_c2 = pW + (size_t)(l * 3 + 2) * MSZ;
    const half_t* pWr_c2 = pW + (size_t)(6 + l * 3 + 2) * MSZ;
    temporal_kernel<<<nb_con + nb_ip, 256, 0, stream>>>(
        cip, ccon,
        rp_all + no_ipip, rp_all + no_csrc, rp_all + no_cdst, col_all,
        pWl_ip, bl_t + (l * 3 + 0) * HDIM, pWr_ip,
        pWl_c1, bl_t + (l * 3 + 1) * HDIM, pWr_c1,
        pWl_c2, bl_t + (l * 3 + 2) * HDIM, pWr_c2,
        Yh_ip, Yh_con, n_ip, n_con, nb_con);

    const half_t* pWl_ic = pW + (size_t)(12 + l * 2 + 0) * MSZ;
    const half_t* pWr_ic = pW + (size_t)(16 + l * 2 + 0) * MSZ;
    const half_t* pWl_ci = pW + (size_t)(12 + l * 2 + 1) * MSZ;
    const half_t* pWr_ci = pW + (size_t)(16 + l * 2 + 1) * MSZ;
    spatial_kernel<<<nb_con + nb_ip, 256, 0, stream>>>(
        Yh_ip, Yh_con,
        rp_all + no_ipcon, rp_all + no_conip, col_all,
        pWl_ic, bl_s + (l * 2 + 0) * HDIM, pWr_ic,
        pWl_ci, bl_s + (l * 2 + 1) * HDIM, pWr_ci,
        xh_ip, xh_con, out_ip, out_con, (l == 1) ? 1 : 0,
        n_ip, n_con, nb_con);

    cip = xh_ip;
    ccon = xh_con;
  }
}